// Round 5
// baseline (1956.383 us; speedup 1.0000x reference)
//
#include <hip/hip_runtime.h>
#include <hip/hip_bf16.h>

typedef __hip_bfloat16 bf16;
typedef __attribute__((ext_vector_type(8))) short short8;
typedef __attribute__((ext_vector_type(4))) float floatx4;

#define BATCH   2
#define SEQ     1024
#define DIM     1024
#define D_INNER 2048
#define D_STATE 16
#define DT_RANK 64
#define MROWS   (BATCH * SEQ)   // 2048

__device__ __forceinline__ float bf2f(bf16 x) { return __bfloat162float(x); }
__device__ __forceinline__ bf16  f2bf(float x) { return __float2bfloat16(x); }
__device__ __forceinline__ short bfbits(float x) {
    bf16 b = __float2bfloat16(x); short s; __builtin_memcpy(&s, &b, 2); return s;
}

// 8 contiguous elements starting at element offset eoff -> 8 bf16 (short8).
// is_f32 is wave-uniform (kernel argument), so the branch is scalar.
__device__ __forceinline__ short8 ld8_any(const void* p, size_t eoff, int is_f32) {
    if (is_f32) {
        const float* f = (const float*)p + eoff;
        floatx4 a = *(const floatx4*)f;
        floatx4 b = *(const floatx4*)(f + 4);
        short8 r;
        r[0] = bfbits(a[0]); r[1] = bfbits(a[1]); r[2] = bfbits(a[2]); r[3] = bfbits(a[3]);
        r[4] = bfbits(b[0]); r[5] = bfbits(b[1]); r[6] = bfbits(b[2]); r[7] = bfbits(b[3]);
        return r;
    } else {
        return *(const short8*)((const bf16*)p + eoff);
    }
}

// ---------------------------------------------------------------------------
// C[m,n] = act( sum_k A[m,k] * B[n,k] + bias[n] )
// A: (M,K) row-major (lda elems), fp32 if a_f32 else bf16 (converted to bf16
// during LDS staging). Same for B (N,K)/b_f32.
// Tile BM=BN=64, BK=32; 256 threads = 4 waves; wave w owns m-rows
// [w*16, w*16+16), iterates 4 n-subtiles of 16.
// mfma_f32_16x16x32_bf16 layouts (HW-verified, learn_hip m89/m91):
//   A/B frag: m(or n) = lane&15, k = (lane>>4)*8 + j  (8 contiguous bf16)
//   D:        col(n)  = lane&15, row(m) = (lane>>4)*4 + reg
// M must be a multiple of 64 (true for all calls: M=2048); N guarded.
// ---------------------------------------------------------------------------
__global__ __launch_bounds__(256) void gemm_bt(
    const void* __restrict__ A, int a_f32, int lda,
    const void* __restrict__ B, int b_f32, int ldb,
    float* __restrict__ Cf, bf16* __restrict__ Cb, int ldc,
    int N, int K,
    const float* __restrict__ bias, int act)
{
    __shared__ short As[64][32];
    __shared__ short Bs[64][32];
    const int m0   = blockIdx.y * 64;
    const int n0   = blockIdx.x * 64;
    const int tid  = threadIdx.x;
    const int wave = tid >> 6;
    const int lane = tid & 63;
    const int srow = tid >> 2;          // staging row 0..63
    const int scol = (tid & 3) << 3;    // staging col 0,8,16,24
    const int r16  = lane & 15;
    const int quad = lane >> 4;

    floatx4 acc[4] = {};

    for (int k0 = 0; k0 < K; k0 += 32) {
        short8 av = ld8_any(A, (size_t)(m0 + srow) * lda + k0 + scol, a_f32);
        short8 bv = {};
        int gn = n0 + srow;
        if (gn < N) bv = ld8_any(B, (size_t)gn * ldb + k0 + scol, b_f32);
        *(short8*)(&As[srow][scol]) = av;
        *(short8*)(&Bs[srow][scol]) = bv;
        __syncthreads();
        short8 af = *(const short8*)(&As[wave * 16 + r16][quad * 8]);
#pragma unroll
        for (int nt = 0; nt < 4; nt++) {
            short8 bq = *(const short8*)(&Bs[nt * 16 + r16][quad * 8]);
            acc[nt] = __builtin_amdgcn_mfma_f32_16x16x32_bf16(af, bq, acc[nt], 0, 0, 0);
        }
        __syncthreads();
    }

#pragma unroll
    for (int nt = 0; nt < 4; nt++) {
        int gn = n0 + nt * 16 + r16;               // D col = lane&15
        if (gn >= N) continue;
        float bsv = bias ? bias[gn] : 0.f;
#pragma unroll
        for (int r = 0; r < 4; r++) {
            int gm = m0 + wave * 16 + quad * 4 + r;  // D row = quad*4 + reg
            float v = acc[nt][r] + bsv;
            if (act == 1) v = (v > 20.f) ? v : log1pf(__expf(v));  // softplus
            size_t o = (size_t)gm * ldc + gn;
            if (Cf) Cf[o] = v;
            if (Cb) Cb[o] = f2bf(v);
        }
    }
}

// ---------------------------------------------------------------------------
// Depthwise causal conv (4 taps) + bias + SiLU over xi = xz[:, :, 0:2048].
// One thread per (b,t,d). conv_w/conv_b read as fp32.
// ---------------------------------------------------------------------------
__global__ __launch_bounds__(256) void conv_silu_k(
    const bf16* __restrict__ xz, const float* __restrict__ cw,
    const float* __restrict__ cb, bf16* __restrict__ xcb)
{
    int idx = blockIdx.x * 256 + threadIdx.x;      // bt*2048 + d
    int d   = idx & (D_INNER - 1);
    int bt  = idx >> 11;
    int t   = bt & (SEQ - 1);
    float s = cb[d];
#pragma unroll
    for (int j = 0; j < 4; j++) {
        int tt = t - 3 + j;
        if (tt >= 0) s += cw[d * 4 + j] * bf2f(xz[(size_t)(bt - 3 + j) * 4096 + d]);
    }
    float sig = 1.f / (1.f + __expf(-s));
    xcb[idx] = f2bf(s * sig);
}

// ---------------------------------------------------------------------------
// Selective scan. One thread per (b, d, n): lane n holds state n of channel d.
// Block = 256 threads = 16 channels x 16 states; one batch per blockIdx.y.
// Per step: h = exp(dt*A)*h + (dt*xc)*B ; y = sum_n h*C via 16-lane butterfly.
// Epilogue fused: y = (y + D*xc) * silu(z), cast bf16 for out-proj GEMM.
// ---------------------------------------------------------------------------
__global__ __launch_bounds__(256) void scan_k(
    const float* __restrict__ dtf, const bf16* __restrict__ xcb,
    const float* __restrict__ xdbl, const bf16* __restrict__ xz,
    const float* __restrict__ Alog, const float* __restrict__ Dp,
    bf16* __restrict__ yb)
{
    const int b = blockIdx.y;
    const int d = blockIdx.x * 16 + (threadIdx.x >> 4);
    const int n = threadIdx.x & 15;
    const float Av = -__expf(Alog[(size_t)d * D_STATE + n]);
    const float Dv = Dp[d];
    float h = 0.f;
    const size_t rbase = (size_t)b * SEQ;
    for (int t = 0; t < SEQ; t++) {
        size_t row = rbase + t;
        float dtv = dtf[row * D_INNER + d];
        float xcv = bf2f(xcb[row * D_INNER + d]);
        float Bv  = xdbl[row * 96 + 64 + n];
        float Cv  = xdbl[row * 96 + 80 + n];
        h = __expf(dtv * Av) * h + (dtv * xcv) * Bv;
        float p = h * Cv;
        p += __shfl_xor(p, 1);
        p += __shfl_xor(p, 2);
        p += __shfl_xor(p, 4);
        p += __shfl_xor(p, 8);
        if (n == 0) {
            float zv = bf2f(xz[row * 4096 + 2048 + d]);
            float y  = (p + Dv * xcv) * (zv / (1.f + __expf(-zv)));
            yb[row * D_INNER + d] = f2bf(y);
        }
    }
}

// ---------------------------------------------------------------------------
// Diagnostic probe (runs LAST). Healthy pipeline => writes NOTHING (test
// passes normally). Anomaly => writes 256*code into out[0] (fp32) so the
// reported absmax error names the dead stage:
//   bit0: xzb dead  bit1: xcb dead  bit2: xdblf dead  bit3: ybf dead
//   bit4: A_log word0 != 0, i.e. inputs are NOT fp32.
// ---------------------------------------------------------------------------
__global__ __launch_bounds__(256) void probe_k(
    const bf16* __restrict__ xzb, const bf16* __restrict__ xcb,
    const float* __restrict__ xdblf, const bf16* __restrict__ ybf,
    const unsigned* __restrict__ alog_raw, float* __restrict__ out)
{
    __shared__ float sm[4][4];
    const int tid = threadIdx.x;
    float m0 = 0.f, m1 = 0.f, m2 = 0.f, m3 = 0.f;
    for (int i = tid; i < 8192; i += 256) {
        m0 = fmaxf(m0, fabsf(bf2f(xzb[i])));
        m1 = fmaxf(m1, fabsf(bf2f(xcb[i])));
        m3 = fmaxf(m3, fabsf(bf2f(ybf[i])));
        if (i < 384) m2 = fmaxf(m2, fabsf(xdblf[i]));
    }
#pragma unroll
    for (int off = 1; off < 64; off <<= 1) {
        m0 = fmaxf(m0, __shfl_xor(m0, off));
        m1 = fmaxf(m1, __shfl_xor(m1, off));
        m2 = fmaxf(m2, __shfl_xor(m2, off));
        m3 = fmaxf(m3, __shfl_xor(m3, off));
    }
    if ((tid & 63) == 0) {
        int w = tid >> 6;
        sm[w][0] = m0; sm[w][1] = m1; sm[w][2] = m2; sm[w][3] = m3;
    }
    __syncthreads();
    if (tid == 0) {
        float a0 = 0.f, a1 = 0.f, a2 = 0.f, a3 = 0.f;
        for (int w = 0; w < 4; w++) {
            a0 = fmaxf(a0, sm[w][0]); a1 = fmaxf(a1, sm[w][1]);
            a2 = fmaxf(a2, sm[w][2]); a3 = fmaxf(a3, sm[w][3]);
        }
        int code = 0;
        if (a0 < 1e-6f) code |= 1;
        if (a1 < 1e-6f) code |= 2;
        if (a2 < 1e-6f) code |= 4;
        if (a3 < 1e-6f) code |= 8;
        if (alog_raw[0] != 0u) code |= 16;   // A_log[0]=log(1)=0.0f iff fp32
        if (code) out[0] = 256.f * (float)code;
    }
}

extern "C" void kernel_launch(void* const* d_in, const int* in_sizes, int n_in,
                              void* d_out, int out_size, void* d_ws, size_t ws_size,
                              hipStream_t stream)
{
    // ALL inputs fp32; OUTPUT IS FP32 (reference returns float32 x).
    const float* x    = (const float*)d_in[0];
    const float* inw  = (const float*)d_in[1];
    const float* cw   = (const float*)d_in[2];
    const float* cb   = (const float*)d_in[3];
    const float* xpw  = (const float*)d_in[4];
    const float* dtw  = (const float*)d_in[5];
    const float* dtb  = (const float*)d_in[6];
    const float* Alog = (const float*)d_in[7];
    const float* Dp   = (const float*)d_in[8];
    const float* ow   = (const float*)d_in[9];
    float* out = (float*)d_out;

    // workspace layout (~55 MB)
    char* p = (char*)d_ws;
    bf16*  xzb   = (bf16*)p;  p += (size_t)MROWS * 4096 * 2;        // 16.8 MB
    bf16*  xcb   = (bf16*)p;  p += (size_t)MROWS * D_INNER * 2;     //  8.4 MB
    float* xdblf = (float*)p; p += (size_t)MROWS * 96 * 4;          //  0.8 MB
    float* dtf   = (float*)p; p += (size_t)MROWS * D_INNER * 4;     // 16.8 MB
    bf16*  ybf   = (bf16*)p;  p += (size_t)MROWS * D_INNER * 2;     //  8.4 MB
    bf16*  xmid  = (bf16*)p;  p += (size_t)MROWS * DIM * 2;         //  4.2 MB

    for (int l = 0; l < 2; l++) {
        const float* inw_l = inw + (size_t)l * 2 * D_INNER * DIM;
        const float* xpw_l = xpw + (size_t)l * 96 * D_INNER;
        const float* dtw_l = dtw + (size_t)l * D_INNER * DT_RANK;
        const float* ow_l  = ow  + (size_t)l * DIM * D_INNER;

        // 1. xz = xin @ in_proj_w^T   (M=2048, N=4096, K=1024), bf16 out
        if (l == 0)
            gemm_bt<<<dim3(64, 32), 256, 0, stream>>>(
                x, 1, DIM, inw_l, 1, DIM,
                nullptr, xzb, 4096, 4096, DIM, nullptr, 0);
        else
            gemm_bt<<<dim3(64, 32), 256, 0, stream>>>(
                xmid, 0, DIM, inw_l, 1, DIM,
                nullptr, xzb, 4096, 4096, DIM, nullptr, 0);

        // 2. causal depthwise conv + bias + SiLU
        conv_silu_k<<<(MROWS * D_INNER) / 256, 256, 0, stream>>>(
            xzb, cw + (size_t)l * D_INNER * 4, cb + (size_t)l * D_INNER, xcb);

        // 3. x_dbl = xc @ x_proj_w^T   (N=96, K=2048), fp32 out
        gemm_bt<<<dim3(2, 32), 256, 0, stream>>>(
            xcb, 0, D_INNER, xpw_l, 1, D_INNER,
            xdblf, nullptr, 96, 96, D_INNER, nullptr, 0);

        // 4. dt = softplus(dt_raw @ dt_proj_w^T + dt_b)  (N=2048, K=64), fp32
        gemm_bt<<<dim3(32, 32), 256, 0, stream>>>(
            xdblf, 1, 96, dtw_l, 1, DT_RANK,
            dtf, nullptr, D_INNER, D_INNER, DT_RANK,
            dtb + (size_t)l * D_INNER, 1);

        // 5. selective scan + gating epilogue
        scan_k<<<dim3(D_INNER / 16, BATCH), 256, 0, stream>>>(
            dtf, xcb, xdblf, xzb,
            Alog + (size_t)l * D_INNER * D_STATE, Dp + (size_t)l * D_INNER, ybf);

        // 6. out = y @ out_proj_w^T   (N=1024, K=2048)
        //    layer 0 -> bf16 xmid; layer 1 -> FP32 d_out (the dtype fix)
        if (l == 0)
            gemm_bt<<<dim3(16, 32), 256, 0, stream>>>(
                ybf, 0, D_INNER, ow_l, 1, D_INNER,
                nullptr, xmid, DIM, DIM, D_INNER, nullptr, 0);
        else
            gemm_bt<<<dim3(16, 32), 256, 0, stream>>>(
                ybf, 0, D_INNER, ow_l, 1, D_INNER,
                out, nullptr, DIM, DIM, D_INNER, nullptr, 0);
    }

    // 7. diagnostic probe — no-op when the pipeline is healthy
    probe_k<<<1, 256, 0, stream>>>(xzb, xcb, xdblf, ybf,
                                   (const unsigned*)Alog, out);
}

// Round 6
// 982.028 us; speedup vs baseline: 1.9922x; 1.9922x over previous
//
#include <hip/hip_runtime.h>
#include <hip/hip_bf16.h>

typedef __hip_bfloat16 bf16;
typedef __attribute__((ext_vector_type(8))) short short8;
typedef __attribute__((ext_vector_type(4))) float floatx4;

#define BATCH   2
#define SEQ     1024
#define DIM     1024
#define D_INNER 2048
#define D_STATE 16
#define DT_RANK 64
#define MROWS   (BATCH * SEQ)   // 2048

__device__ __forceinline__ float bf2f(bf16 x) { return __bfloat162float(x); }
__device__ __forceinline__ bf16  f2bf(float x) { return __float2bfloat16(x); }
__device__ __forceinline__ short bfbits(float x) {
    bf16 b = __float2bfloat16(x); short s; __builtin_memcpy(&s, &b, 2); return s;
}

// 8 contiguous elements starting at element offset eoff -> 8 bf16 (short8).
// is_f32 is wave-uniform (kernel argument), so the branch is scalar.
__device__ __forceinline__ short8 ld8_any(const void* p, size_t eoff, int is_f32) {
    if (is_f32) {
        const float* f = (const float*)p + eoff;
        floatx4 a = *(const floatx4*)f;
        floatx4 b = *(const floatx4*)(f + 4);
        short8 r;
        r[0] = bfbits(a[0]); r[1] = bfbits(a[1]); r[2] = bfbits(a[2]); r[3] = bfbits(a[3]);
        r[4] = bfbits(b[0]); r[5] = bfbits(b[1]); r[6] = bfbits(b[2]); r[7] = bfbits(b[3]);
        return r;
    } else {
        return *(const short8*)((const bf16*)p + eoff);
    }
}

// ---------------------------------------------------------------------------
// C[m,n] = act( sum_k A[m,k] * B[n,k] + bias[n] )
// A: (M,K) row-major (lda elems), fp32 if a_f32 else bf16 (converted to bf16
// during LDS staging). Same for B (N,K)/b_f32.
// Tile BM=BN=64, BK=32; 256 threads = 4 waves; wave w owns m-rows
// [w*16, w*16+16), iterates 4 n-subtiles of 16.
// mfma_f32_16x16x32_bf16 layouts (HW-verified, learn_hip m89/m91):
//   A/B frag: m(or n) = lane&15, k = (lane>>4)*8 + j  (8 contiguous bf16)
//   D:        col(n)  = lane&15, row(m) = (lane>>4)*4 + reg
// ---------------------------------------------------------------------------
__global__ __launch_bounds__(256) void gemm_bt(
    const void* __restrict__ A, int a_f32, int lda,
    const void* __restrict__ B, int b_f32, int ldb,
    float* __restrict__ Cf, bf16* __restrict__ Cb, int ldc,
    int N, int K,
    const float* __restrict__ bias, int act)
{
    __shared__ short As[64][32];
    __shared__ short Bs[64][32];
    const int m0   = blockIdx.y * 64;
    const int n0   = blockIdx.x * 64;
    const int tid  = threadIdx.x;
    const int wave = tid >> 6;
    const int lane = tid & 63;
    const int srow = tid >> 2;          // staging row 0..63
    const int scol = (tid & 3) << 3;    // staging col 0,8,16,24
    const int r16  = lane & 15;
    const int quad = lane >> 4;

    floatx4 acc[4] = {};

    for (int k0 = 0; k0 < K; k0 += 32) {
        short8 av = ld8_any(A, (size_t)(m0 + srow) * lda + k0 + scol, a_f32);
        short8 bv = {};
        int gn = n0 + srow;
        if (gn < N) bv = ld8_any(B, (size_t)gn * ldb + k0 + scol, b_f32);
        *(short8*)(&As[srow][scol]) = av;
        *(short8*)(&Bs[srow][scol]) = bv;
        __syncthreads();
        short8 af = *(const short8*)(&As[wave * 16 + r16][quad * 8]);
#pragma unroll
        for (int nt = 0; nt < 4; nt++) {
            short8 bq = *(const short8*)(&Bs[nt * 16 + r16][quad * 8]);
            acc[nt] = __builtin_amdgcn_mfma_f32_16x16x32_bf16(af, bq, acc[nt], 0, 0, 0);
        }
        __syncthreads();
    }

#pragma unroll
    for (int nt = 0; nt < 4; nt++) {
        int gn = n0 + nt * 16 + r16;               // D col = lane&15
        if (gn >= N) continue;
        float bsv = bias ? bias[gn] : 0.f;
#pragma unroll
        for (int r = 0; r < 4; r++) {
            int gm = m0 + wave * 16 + quad * 4 + r;  // D row = quad*4 + reg
            float v = acc[nt][r] + bsv;
            if (act == 1) v = (v > 20.f) ? v : log1pf(__expf(v));  // softplus
            size_t o = (size_t)gm * ldc + gn;
            if (Cf) Cf[o] = v;
            if (Cb) Cb[o] = f2bf(v);
        }
    }
}

// ---------------------------------------------------------------------------
// Depthwise causal conv (4 taps) + bias + SiLU over xi = xz[:, :, 0:2048].
// One thread per (b,t,d). conv_w/conv_b read as fp32.
// ---------------------------------------------------------------------------
__global__ __launch_bounds__(256) void conv_silu_k(
    const bf16* __restrict__ xz, const float* __restrict__ cw,
    const float* __restrict__ cb, bf16* __restrict__ xcb)
{
    int idx = blockIdx.x * 256 + threadIdx.x;      // bt*2048 + d
    int d   = idx & (D_INNER - 1);
    int bt  = idx >> 11;
    int t   = bt & (SEQ - 1);
    float s = cb[d];
#pragma unroll
    for (int j = 0; j < 4; j++) {
        int tt = t - 3 + j;
        if (tt >= 0) s += cw[d * 4 + j] * bf2f(xz[(size_t)(bt - 3 + j) * 4096 + d]);
    }
    float sig = 1.f / (1.f + __expf(-s));
    xcb[idx] = f2bf(s * sig);
}

// ---------------------------------------------------------------------------
// Selective scan v2: chunked LDS staging (R5 profile: v1 was latency-bound,
// 742us at 1% HBM BW / 8.7% VALUBusy — serial dependent global loads).
// Block = 256 threads = 16 channels (dl) x 16 states (n); one (b, d-group).
// Per chunk of 64 timesteps: cooperatively stage dt/xc/B/C/z into LDS
// (coalesced), scan 64 steps entirely from LDS (broadcast reads, no bank
// conflicts), then write gated y via LDS coalesced.
// ---------------------------------------------------------------------------
__global__ __launch_bounds__(256) void scan_k(
    const float* __restrict__ dtf, const bf16* __restrict__ xcb,
    const float* __restrict__ xdbl, const bf16* __restrict__ xz,
    const float* __restrict__ Alog, const float* __restrict__ Dp,
    bf16* __restrict__ yb)
{
    __shared__ float dt_s[64][16];
    __shared__ float xc_s[64][16];
    __shared__ float B_s[64][16];
    __shared__ float C_s[64][16];
    __shared__ float z_s[64][16];
    __shared__ float y_s[64][16];

    const int b   = blockIdx.y;
    const int d0  = blockIdx.x * 16;
    const int tid = threadIdx.x;
    const int dl  = tid >> 4;       // channel 0..15
    const int n   = tid & 15;       // state 0..15
    const float Av   = -__expf(Alog[(size_t)(d0 + dl) * D_STATE + n]);
    const float Dv_w = Dp[d0 + (tid & 15)];   // for writeback lanes (i==tid&15)
    float h = 0.f;
    const size_t rbase = (size_t)b * SEQ;

    for (int c = 0; c < SEQ / 64; c++) {
        const int t0 = c * 64;
        __syncthreads();   // previous chunk's writeback reads done
#pragma unroll
        for (int e = tid; e < 1024; e += 256) {
            int t = e >> 4, i = e & 15;
            size_t row = rbase + t0 + t;
            dt_s[t][i] = dtf[row * D_INNER + d0 + i];
            xc_s[t][i] = bf2f(xcb[row * D_INNER + d0 + i]);
            B_s[t][i]  = xdbl[row * 96 + 64 + i];
            C_s[t][i]  = xdbl[row * 96 + 80 + i];
            z_s[t][i]  = bf2f(xz[row * 4096 + 2048 + d0 + i]);
        }
        __syncthreads();
#pragma unroll 4
        for (int t = 0; t < 64; t++) {
            float dtv = dt_s[t][dl];
            float xcv = xc_s[t][dl];
            float Bv  = B_s[t][n];
            float Cv  = C_s[t][n];
            h = __expf(dtv * Av) * h + (dtv * xcv) * Bv;
            float p = h * Cv;
            p += __shfl_xor(p, 1);
            p += __shfl_xor(p, 2);
            p += __shfl_xor(p, 4);
            p += __shfl_xor(p, 8);
            if (n == 0) y_s[t][dl] = p;
        }
        __syncthreads();
#pragma unroll
        for (int e = tid; e < 1024; e += 256) {
            int t = e >> 4, i = e & 15;
            size_t row = rbase + t0 + t;
            float xcv = xc_s[t][i];
            float zv  = z_s[t][i];
            float y   = (y_s[t][i] + Dv_w * xcv) * (zv / (1.f + __expf(-zv)));
            yb[row * D_INNER + d0 + i] = f2bf(y);
        }
    }
}

extern "C" void kernel_launch(void* const* d_in, const int* in_sizes, int n_in,
                              void* d_out, int out_size, void* d_ws, size_t ws_size,
                              hipStream_t stream)
{
    // ALL inputs fp32; OUTPUT IS FP32 (reference returns float32 x).
    const float* x    = (const float*)d_in[0];
    const float* inw  = (const float*)d_in[1];
    const float* cw   = (const float*)d_in[2];
    const float* cb   = (const float*)d_in[3];
    const float* xpw  = (const float*)d_in[4];
    const float* dtw  = (const float*)d_in[5];
    const float* dtb  = (const float*)d_in[6];
    const float* Alog = (const float*)d_in[7];
    const float* Dp   = (const float*)d_in[8];
    const float* ow   = (const float*)d_in[9];
    float* out = (float*)d_out;

    // workspace layout (~55 MB)
    char* p = (char*)d_ws;
    bf16*  xzb   = (bf16*)p;  p += (size_t)MROWS * 4096 * 2;        // 16.8 MB
    bf16*  xcb   = (bf16*)p;  p += (size_t)MROWS * D_INNER * 2;     //  8.4 MB
    float* xdblf = (float*)p; p += (size_t)MROWS * 96 * 4;          //  0.8 MB
    float* dtf   = (float*)p; p += (size_t)MROWS * D_INNER * 4;     // 16.8 MB
    bf16*  ybf   = (bf16*)p;  p += (size_t)MROWS * D_INNER * 2;     //  8.4 MB
    bf16*  xmid  = (bf16*)p;  p += (size_t)MROWS * DIM * 2;         //  4.2 MB

    for (int l = 0; l < 2; l++) {
        const float* inw_l = inw + (size_t)l * 2 * D_INNER * DIM;
        const float* xpw_l = xpw + (size_t)l * 96 * D_INNER;
        const float* dtw_l = dtw + (size_t)l * D_INNER * DT_RANK;
        const float* ow_l  = ow  + (size_t)l * DIM * D_INNER;

        // 1. xz = xin @ in_proj_w^T   (M=2048, N=4096, K=1024), bf16 out
        if (l == 0)
            gemm_bt<<<dim3(64, 32), 256, 0, stream>>>(
                x, 1, DIM, inw_l, 1, DIM,
                nullptr, xzb, 4096, 4096, DIM, nullptr, 0);
        else
            gemm_bt<<<dim3(64, 32), 256, 0, stream>>>(
                xmid, 0, DIM, inw_l, 1, DIM,
                nullptr, xzb, 4096, 4096, DIM, nullptr, 0);

        // 2. causal depthwise conv + bias + SiLU
        conv_silu_k<<<(MROWS * D_INNER) / 256, 256, 0, stream>>>(
            xzb, cw + (size_t)l * D_INNER * 4, cb + (size_t)l * D_INNER, xcb);

        // 3. x_dbl = xc @ x_proj_w^T   (N=96, K=2048), fp32 out
        gemm_bt<<<dim3(2, 32), 256, 0, stream>>>(
            xcb, 0, D_INNER, xpw_l, 1, D_INNER,
            xdblf, nullptr, 96, 96, D_INNER, nullptr, 0);

        // 4. dt = softplus(dt_raw @ dt_proj_w^T + dt_b)  (N=2048, K=64), fp32
        gemm_bt<<<dim3(32, 32), 256, 0, stream>>>(
            xdblf, 1, 96, dtw_l, 1, DT_RANK,
            dtf, nullptr, D_INNER, D_INNER, DT_RANK,
            dtb + (size_t)l * D_INNER, 1);

        // 5. selective scan + gating epilogue (LDS-chunked)
        scan_k<<<dim3(D_INNER / 16, BATCH), 256, 0, stream>>>(
            dtf, xcb, xdblf, xzb,
            Alog + (size_t)l * D_INNER * D_STATE, Dp + (size_t)l * D_INNER, ybf);

        // 6. out = y @ out_proj_w^T   (N=1024, K=2048)
        if (l == 0)
            gemm_bt<<<dim3(16, 32), 256, 0, stream>>>(
                ybf, 0, D_INNER, ow_l, 1, D_INNER,
                nullptr, xmid, DIM, DIM, D_INNER, nullptr, 0);
        else
            gemm_bt<<<dim3(16, 32), 256, 0, stream>>>(
                ybf, 0, D_INNER, ow_l, 1, D_INNER,
                out, nullptr, DIM, DIM, D_INNER, nullptr, 0);
    }
}

// Round 7
// 833.049 us; speedup vs baseline: 2.3485x; 1.1788x over previous
//
#include <hip/hip_runtime.h>
#include <hip/hip_bf16.h>

typedef __hip_bfloat16 bf16;
typedef __attribute__((ext_vector_type(8))) short short8;
typedef __attribute__((ext_vector_type(4))) float floatx4;

#define BATCH   2
#define SEQ     1024
#define DIM     1024
#define D_INNER 2048
#define D_STATE 16
#define DT_RANK 64
#define MROWS   (BATCH * SEQ)   // 2048
#define CHUNK   128
#define NCHUNK  (SEQ / CHUNK)   // 8

__device__ __forceinline__ float bf2f(bf16 x) { return __bfloat162float(x); }
__device__ __forceinline__ bf16  f2bf(float x) { return __float2bfloat16(x); }
__device__ __forceinline__ short bfbits(float x) {
    bf16 b = __float2bfloat16(x); short s; __builtin_memcpy(&s, &b, 2); return s;
}

// 8 contiguous elements starting at element offset eoff -> 8 bf16 (short8).
__device__ __forceinline__ short8 ld8_any(const void* p, size_t eoff, int is_f32) {
    if (is_f32) {
        const float* f = (const float*)p + eoff;
        floatx4 a = *(const floatx4*)f;
        floatx4 b = *(const floatx4*)(f + 4);
        short8 r;
        r[0] = bfbits(a[0]); r[1] = bfbits(a[1]); r[2] = bfbits(a[2]); r[3] = bfbits(a[3]);
        r[4] = bfbits(b[0]); r[5] = bfbits(b[1]); r[6] = bfbits(b[2]); r[7] = bfbits(b[3]);
        return r;
    } else {
        return *(const short8*)((const bf16*)p + eoff);
    }
}

// ---------------------------------------------------------------------------
// C[m,n] = act( sum_k A[m,k] * B[n,k] + bias[n] ); MFMA 16x16x32 bf16.
// Tile BM=BN=64, BK=32; 256 threads = 4 waves. (layouts verified m89/m91)
// ---------------------------------------------------------------------------
__global__ __launch_bounds__(256) void gemm_bt(
    const void* __restrict__ A, int a_f32, int lda,
    const void* __restrict__ B, int b_f32, int ldb,
    float* __restrict__ Cf, bf16* __restrict__ Cb, int ldc,
    int N, int K,
    const float* __restrict__ bias, int act)
{
    __shared__ short As[64][32];
    __shared__ short Bs[64][32];
    const int m0   = blockIdx.y * 64;
    const int n0   = blockIdx.x * 64;
    const int tid  = threadIdx.x;
    const int wave = tid >> 6;
    const int lane = tid & 63;
    const int srow = tid >> 2;
    const int scol = (tid & 3) << 3;
    const int r16  = lane & 15;
    const int quad = lane >> 4;

    floatx4 acc[4] = {};

    for (int k0 = 0; k0 < K; k0 += 32) {
        short8 av = ld8_any(A, (size_t)(m0 + srow) * lda + k0 + scol, a_f32);
        short8 bv = {};
        int gn = n0 + srow;
        if (gn < N) bv = ld8_any(B, (size_t)gn * ldb + k0 + scol, b_f32);
        *(short8*)(&As[srow][scol]) = av;
        *(short8*)(&Bs[srow][scol]) = bv;
        __syncthreads();
        short8 af = *(const short8*)(&As[wave * 16 + r16][quad * 8]);
#pragma unroll
        for (int nt = 0; nt < 4; nt++) {
            short8 bq = *(const short8*)(&Bs[nt * 16 + r16][quad * 8]);
            acc[nt] = __builtin_amdgcn_mfma_f32_16x16x32_bf16(af, bq, acc[nt], 0, 0, 0);
        }
        __syncthreads();
    }

#pragma unroll
    for (int nt = 0; nt < 4; nt++) {
        int gn = n0 + nt * 16 + r16;
        if (gn >= N) continue;
        float bsv = bias ? bias[gn] : 0.f;
#pragma unroll
        for (int r = 0; r < 4; r++) {
            int gm = m0 + wave * 16 + quad * 4 + r;
            float v = acc[nt][r] + bsv;
            if (act == 1) v = (v > 20.f) ? v : log1pf(__expf(v));  // softplus
            size_t o = (size_t)gm * ldc + gn;
            if (Cf) Cf[o] = v;
            if (Cb) Cb[o] = f2bf(v);
        }
    }
}

// ---------------------------------------------------------------------------
// Depthwise causal conv (4 taps) + bias + SiLU over xi = xz[:, :, 0:2048].
// ---------------------------------------------------------------------------
__global__ __launch_bounds__(256) void conv_silu_k(
    const bf16* __restrict__ xz, const float* __restrict__ cw,
    const float* __restrict__ cb, bf16* __restrict__ xcb)
{
    int idx = blockIdx.x * 256 + threadIdx.x;      // bt*2048 + d
    int d   = idx & (D_INNER - 1);
    int bt  = idx >> 11;
    int t   = bt & (SEQ - 1);
    float s = cb[d];
#pragma unroll
    for (int j = 0; j < 4; j++) {
        int tt = t - 3 + j;
        if (tt >= 0) s += cw[d * 4 + j] * bf2f(xz[(size_t)(bt - 3 + j) * 4096 + d]);
    }
    float sig = 1.f / (1.f + __expf(-s));
    xcb[idx] = f2bf(s * sig);
}

// ---------------------------------------------------------------------------
// Selective scan v3: chunk-parallel, channel-per-thread (R6 post-mortem:
// v2's per-step 4-deep shuffle chain at 1 wave/SIMD was latency-bound).
// Thread owns channel d, h[16] in registers; time split into 8 chunks of 128
// processed by independent blocks. Stage 1: scan chunk from h=0 -> S[16],
// plus sum(dt) (chunk decay = exp(A*sum dt), analytic). Stage 2: rebuild
// h_init by combining earlier chunks' (S, sdt), re-scan chunk, fuse y-dot +
// D*xc + silu(z) gating.
// Grid: (D_INNER/256, BATCH, NCHUNK) = 8 x 2 x 8 = 128 blocks x 256 thr.
// ---------------------------------------------------------------------------
__global__ __launch_bounds__(256) void scan1_k(
    const float* __restrict__ dtf, const bf16* __restrict__ xcb,
    const float* __restrict__ xdbl, const float* __restrict__ Alog,
    float* __restrict__ chunk_sdt, float* __restrict__ chunk_S)
{
    __shared__ float B_s[CHUNK][16];
    const int d  = blockIdx.x * 256 + threadIdx.x;
    const int b  = blockIdx.y;
    const int c  = blockIdx.z;
    const size_t rbase = (size_t)b * SEQ + c * CHUNK;

    for (int e = threadIdx.x; e < CHUNK * 16; e += 256) {
        int t = e >> 4, n = e & 15;
        B_s[t][n] = xdbl[(rbase + t) * 96 + 64 + n];
    }
    float A[16];
#pragma unroll
    for (int n = 0; n < 16; n++) A[n] = -__expf(Alog[(size_t)d * 16 + n]);
    float h[16] = {};
    float sdt = 0.f;
    __syncthreads();

    for (int t = 0; t < CHUNK; t++) {
        float dtv = dtf[(rbase + t) * D_INNER + d];
        float xcv = bf2f(xcb[(rbase + t) * D_INNER + d]);
        float u = dtv * xcv;
        sdt += dtv;
#pragma unroll
        for (int n = 0; n < 16; n++)
            h[n] = __expf(dtv * A[n]) * h[n] + u * B_s[t][n];
    }
    chunk_sdt[(b * NCHUNK + c) * D_INNER + d] = sdt;
#pragma unroll
    for (int n = 0; n < 16; n++)
        chunk_S[((size_t)(b * NCHUNK + c) * 16 + n) * D_INNER + d] = h[n];
}

__global__ __launch_bounds__(256) void scan2_k(
    const float* __restrict__ dtf, const bf16* __restrict__ xcb,
    const float* __restrict__ xdbl, const bf16* __restrict__ xz,
    const float* __restrict__ Alog, const float* __restrict__ Dp,
    const float* __restrict__ chunk_sdt, const float* __restrict__ chunk_S,
    bf16* __restrict__ yb)
{
    __shared__ float B_s[CHUNK][16];
    __shared__ float C_s[CHUNK][16];
    const int d  = blockIdx.x * 256 + threadIdx.x;
    const int b  = blockIdx.y;
    const int c  = blockIdx.z;
    const size_t rbase = (size_t)b * SEQ + c * CHUNK;

    for (int e = threadIdx.x; e < CHUNK * 16; e += 256) {
        int t = e >> 4, n = e & 15;
        B_s[t][n] = xdbl[(rbase + t) * 96 + 64 + n];
        C_s[t][n] = xdbl[(rbase + t) * 96 + 80 + n];
    }
    float A[16];
#pragma unroll
    for (int n = 0; n < 16; n++) A[n] = -__expf(Alog[(size_t)d * 16 + n]);

    // rebuild h_init from earlier chunks (c is block-uniform -> no divergence)
    float h[16] = {};
    for (int j = 0; j < c; j++) {
        float sdt = chunk_sdt[(b * NCHUNK + j) * D_INNER + d];
#pragma unroll
        for (int n = 0; n < 16; n++) {
            float S = chunk_S[((size_t)(b * NCHUNK + j) * 16 + n) * D_INNER + d];
            h[n] = __expf(sdt * A[n]) * h[n] + S;
        }
    }
    const float Dv = Dp[d];
    __syncthreads();

    for (int t = 0; t < CHUNK; t++) {
        size_t row = rbase + t;
        float dtv = dtf[row * D_INNER + d];
        float xcv = bf2f(xcb[row * D_INNER + d]);
        float u = dtv * xcv;
        float y = 0.f;
#pragma unroll
        for (int n = 0; n < 16; n++) {
            h[n] = __expf(dtv * A[n]) * h[n] + u * B_s[t][n];
            y += h[n] * C_s[t][n];
        }
        float zv = bf2f(xz[row * 4096 + 2048 + d]);
        y = (y + Dv * xcv) * (zv / (1.f + __expf(-zv)));
        yb[row * D_INNER + d] = f2bf(y);
    }
}

extern "C" void kernel_launch(void* const* d_in, const int* in_sizes, int n_in,
                              void* d_out, int out_size, void* d_ws, size_t ws_size,
                              hipStream_t stream)
{
    // ALL inputs fp32; OUTPUT IS FP32.
    const float* x    = (const float*)d_in[0];
    const float* inw  = (const float*)d_in[1];
    const float* cw   = (const float*)d_in[2];
    const float* cb   = (const float*)d_in[3];
    const float* xpw  = (const float*)d_in[4];
    const float* dtw  = (const float*)d_in[5];
    const float* dtb  = (const float*)d_in[6];
    const float* Alog = (const float*)d_in[7];
    const float* Dp   = (const float*)d_in[8];
    const float* ow   = (const float*)d_in[9];
    float* out = (float*)d_out;

    // workspace layout (~58 MB)
    char* p = (char*)d_ws;
    bf16*  xzb   = (bf16*)p;  p += (size_t)MROWS * 4096 * 2;        // 16.8 MB
    bf16*  xcb   = (bf16*)p;  p += (size_t)MROWS * D_INNER * 2;     //  8.4 MB
    float* xdblf = (float*)p; p += (size_t)MROWS * 96 * 4;          //  0.8 MB
    float* dtf   = (float*)p; p += (size_t)MROWS * D_INNER * 4;     // 16.8 MB
    bf16*  ybf   = (bf16*)p;  p += (size_t)MROWS * D_INNER * 2;     //  8.4 MB
    bf16*  xmid  = (bf16*)p;  p += (size_t)MROWS * DIM * 2;         //  4.2 MB
    float* csdt  = (float*)p; p += (size_t)BATCH * NCHUNK * D_INNER * 4;      // 0.13 MB
    float* cS    = (float*)p; p += (size_t)BATCH * NCHUNK * 16 * D_INNER * 4; // 2.1 MB

    for (int l = 0; l < 2; l++) {
        const float* inw_l = inw + (size_t)l * 2 * D_INNER * DIM;
        const float* xpw_l = xpw + (size_t)l * 96 * D_INNER;
        const float* dtw_l = dtw + (size_t)l * D_INNER * DT_RANK;
        const float* ow_l  = ow  + (size_t)l * DIM * D_INNER;
        const float* Al    = Alog + (size_t)l * D_INNER * D_STATE;

        // 1. xz = xin @ in_proj_w^T   (M=2048, N=4096, K=1024), bf16 out
        if (l == 0)
            gemm_bt<<<dim3(64, 32), 256, 0, stream>>>(
                x, 1, DIM, inw_l, 1, DIM,
                nullptr, xzb, 4096, 4096, DIM, nullptr, 0);
        else
            gemm_bt<<<dim3(64, 32), 256, 0, stream>>>(
                xmid, 0, DIM, inw_l, 1, DIM,
                nullptr, xzb, 4096, 4096, DIM, nullptr, 0);

        // 2. causal depthwise conv + bias + SiLU
        conv_silu_k<<<(MROWS * D_INNER) / 256, 256, 0, stream>>>(
            xzb, cw + (size_t)l * D_INNER * 4, cb + (size_t)l * D_INNER, xcb);

        // 3. x_dbl = xc @ x_proj_w^T   (N=96, K=2048), fp32 out
        gemm_bt<<<dim3(2, 32), 256, 0, stream>>>(
            xcb, 0, D_INNER, xpw_l, 1, D_INNER,
            xdblf, nullptr, 96, 96, D_INNER, nullptr, 0);

        // 4. dt = softplus(dt_raw @ dt_proj_w^T + dt_b)  (N=2048, K=64), fp32
        gemm_bt<<<dim3(32, 32), 256, 0, stream>>>(
            xdblf, 1, 96, dtw_l, 1, DT_RANK,
            dtf, nullptr, D_INNER, D_INNER, DT_RANK,
            dtb + (size_t)l * D_INNER, 1);

        // 5. chunk-parallel selective scan (2 stages) + gating epilogue
        scan1_k<<<dim3(D_INNER / 256, BATCH, NCHUNK), 256, 0, stream>>>(
            dtf, xcb, xdblf, Al, csdt, cS);
        scan2_k<<<dim3(D_INNER / 256, BATCH, NCHUNK), 256, 0, stream>>>(
            dtf, xcb, xdblf, xzb, Al, Dp + (size_t)l * D_INNER,
            csdt, cS, ybf);

        // 6. out = y @ out_proj_w^T   (N=1024, K=2048)
        if (l == 0)
            gemm_bt<<<dim3(16, 32), 256, 0, stream>>>(
                ybf, 0, D_INNER, ow_l, 1, D_INNER,
                nullptr, xmid, DIM, DIM, D_INNER, nullptr, 0);
        else
            gemm_bt<<<dim3(16, 32), 256, 0, stream>>>(
                ybf, 0, D_INNER, ow_l, 1, D_INNER,
                out, nullptr, DIM, DIM, D_INNER, nullptr, 0);
    }
}

// Round 8
// 586.231 us; speedup vs baseline: 3.3372x; 1.4210x over previous
//
#include <hip/hip_runtime.h>
#include <hip/hip_bf16.h>

typedef __hip_bfloat16 bf16;
typedef __attribute__((ext_vector_type(8))) short short8;
typedef __attribute__((ext_vector_type(4))) float floatx4;

#define BATCH   2
#define SEQ     1024
#define DIM     1024
#define D_INNER 2048
#define D_STATE 16
#define DT_RANK 64
#define MROWS   (BATCH * SEQ)   // 2048
#define CHUNK   32
#define NCHUNK  (SEQ / CHUNK)   // 32

__device__ __forceinline__ float bf2f(bf16 x) { return __bfloat162float(x); }
__device__ __forceinline__ bf16  f2bf(float x) { return __float2bfloat16(x); }
__device__ __forceinline__ short bfbits(float x) {
    bf16 b = __float2bfloat16(x); short s; __builtin_memcpy(&s, &b, 2); return s;
}

// 8 contiguous elements starting at element offset eoff -> 8 bf16 (short8).
__device__ __forceinline__ short8 ld8_any(const void* p, size_t eoff, int is_f32) {
    if (is_f32) {
        const float* f = (const float*)p + eoff;
        floatx4 a = *(const floatx4*)f;
        floatx4 b = *(const floatx4*)(f + 4);
        short8 r;
        r[0] = bfbits(a[0]); r[1] = bfbits(a[1]); r[2] = bfbits(a[2]); r[3] = bfbits(a[3]);
        r[4] = bfbits(b[0]); r[5] = bfbits(b[1]); r[6] = bfbits(b[2]); r[7] = bfbits(b[3]);
        return r;
    } else {
        return *(const short8*)((const bf16*)p + eoff);
    }
}

// ---------------------------------------------------------------------------
// C[m,n] = act( sum_k A[m,k] * B[n,k] + bias[n] ); MFMA 16x16x32 bf16.
// Tile BM=BN=64, BK=32; 256 threads = 4 waves. (layouts verified m89/m91)
// ---------------------------------------------------------------------------
__global__ __launch_bounds__(256) void gemm_bt(
    const void* __restrict__ A, int a_f32, int lda,
    const void* __restrict__ B, int b_f32, int ldb,
    float* __restrict__ Cf, bf16* __restrict__ Cb, int ldc,
    int N, int K,
    const float* __restrict__ bias, int act)
{
    __shared__ short As[64][32];
    __shared__ short Bs[64][32];
    const int m0   = blockIdx.y * 64;
    const int n0   = blockIdx.x * 64;
    const int tid  = threadIdx.x;
    const int wave = tid >> 6;
    const int lane = tid & 63;
    const int srow = tid >> 2;
    const int scol = (tid & 3) << 3;
    const int r16  = lane & 15;
    const int quad = lane >> 4;

    floatx4 acc[4] = {};

    for (int k0 = 0; k0 < K; k0 += 32) {
        short8 av = ld8_any(A, (size_t)(m0 + srow) * lda + k0 + scol, a_f32);
        short8 bv = {};
        int gn = n0 + srow;
        if (gn < N) bv = ld8_any(B, (size_t)gn * ldb + k0 + scol, b_f32);
        *(short8*)(&As[srow][scol]) = av;
        *(short8*)(&Bs[srow][scol]) = bv;
        __syncthreads();
        short8 af = *(const short8*)(&As[wave * 16 + r16][quad * 8]);
#pragma unroll
        for (int nt = 0; nt < 4; nt++) {
            short8 bq = *(const short8*)(&Bs[nt * 16 + r16][quad * 8]);
            acc[nt] = __builtin_amdgcn_mfma_f32_16x16x32_bf16(af, bq, acc[nt], 0, 0, 0);
        }
        __syncthreads();
    }

#pragma unroll
    for (int nt = 0; nt < 4; nt++) {
        int gn = n0 + nt * 16 + r16;
        if (gn >= N) continue;
        float bsv = bias ? bias[gn] : 0.f;
#pragma unroll
        for (int r = 0; r < 4; r++) {
            int gm = m0 + wave * 16 + quad * 4 + r;
            float v = acc[nt][r] + bsv;
            if (act == 1) v = (v > 20.f) ? v : log1pf(__expf(v));  // softplus
            size_t o = (size_t)gm * ldc + gn;
            if (Cf) Cf[o] = v;
            if (Cb) Cb[o] = f2bf(v);
        }
    }
}

// ---------------------------------------------------------------------------
// Depthwise causal conv (4 taps) + bias + SiLU over xi = xz[:, :, 0:2048].
// ---------------------------------------------------------------------------
__global__ __launch_bounds__(256) void conv_silu_k(
    const bf16* __restrict__ xz, const float* __restrict__ cw,
    const float* __restrict__ cb, bf16* __restrict__ xcb)
{
    int idx = blockIdx.x * 256 + threadIdx.x;      // bt*2048 + d
    int d   = idx & (D_INNER - 1);
    int bt  = idx >> 11;
    int t   = bt & (SEQ - 1);
    float s = cb[d];
#pragma unroll
    for (int j = 0; j < 4; j++) {
        int tt = t - 3 + j;
        if (tt >= 0) s += cw[d * 4 + j] * bf2f(xz[(size_t)(bt - 3 + j) * 4096 + d]);
    }
    float sig = 1.f / (1.f + __expf(-s));
    xcb[idx] = f2bf(s * sig);
}

// ---------------------------------------------------------------------------
// Selective scan v4 (R7 post-mortem: v3 was latency-bound — per-step
// dependent global dt/xc loads at 0.5 blocks/CU, VALUBusy 12%).
// Changes: CHUNK 128->32 (grid 512 blocks = 2/CU, 8 waves/CU) and bulk LDS
// staging of the dt/xc tile per block (coalesced, pipelined), so the serial
// t-loop runs entirely from LDS/registers.
// Thread owns channel d; h[16] in VGPRs; y-dot is 16 in-register FMAs.
// Stage 1: chunk-local scan from h=0 -> S[16], sum(dt)  (chunk decay is
// analytic: exp(A*sum dt)). Stage 2: rebuild h_init from earlier chunks'
// (S, sdt), re-scan chunk, fuse y-dot + D*xc + silu(z) gating.
// LDS: dt 32KB fp32 + xc 16KB bf16 + B/C 2KB ea = 50/52KB -> 3 blocks/CU.
// ---------------------------------------------------------------------------
__global__ __launch_bounds__(256) void scan1_k(
    const float* __restrict__ dtf, const bf16* __restrict__ xcb,
    const float* __restrict__ xdbl, const float* __restrict__ Alog,
    float* __restrict__ chunk_sdt, float* __restrict__ chunk_S)
{
    __shared__ float dt_s[CHUNK][256];
    __shared__ short xc_s[CHUNK][256];
    __shared__ float B_s[CHUNK][16];
    const int tid = threadIdx.x;
    const int d0  = blockIdx.x * 256;
    const int d   = d0 + tid;
    const int b   = blockIdx.y;
    const int c   = blockIdx.z;
    const size_t rbase = (size_t)b * SEQ + c * CHUNK;

#pragma unroll 4
    for (int t = 0; t < CHUNK; t++) {            // e = t*256 + tid, coalesced
        dt_s[t][tid] = dtf[(rbase + t) * D_INNER + d0 + tid];
        ((short*)xc_s)[t * 256 + tid] = *(const short*)&xcb[(rbase + t) * D_INNER + d0 + tid];
    }
    for (int e = tid; e < CHUNK * 16; e += 256) {
        int t = e >> 4, n = e & 15;
        B_s[t][n] = xdbl[(rbase + t) * 96 + 64 + n];
    }
    float A[16];
#pragma unroll
    for (int n = 0; n < 16; n++) A[n] = -__expf(Alog[(size_t)d * 16 + n]);
    float h[16] = {};
    float sdt = 0.f;
    __syncthreads();

    for (int t = 0; t < CHUNK; t++) {
        float dtv = dt_s[t][tid];
        bf16 xcr; short xs = xc_s[t][tid]; __builtin_memcpy(&xcr, &xs, 2);
        float u = dtv * bf2f(xcr);
        sdt += dtv;
        floatx4 B0 = *(const floatx4*)&B_s[t][0];
        floatx4 B1 = *(const floatx4*)&B_s[t][4];
        floatx4 B2 = *(const floatx4*)&B_s[t][8];
        floatx4 B3 = *(const floatx4*)&B_s[t][12];
#pragma unroll
        for (int n = 0; n < 4; n++) {
            h[n]      = __expf(dtv * A[n])      * h[n]      + u * B0[n];
            h[n + 4]  = __expf(dtv * A[n + 4])  * h[n + 4]  + u * B1[n];
            h[n + 8]  = __expf(dtv * A[n + 8])  * h[n + 8]  + u * B2[n];
            h[n + 12] = __expf(dtv * A[n + 12]) * h[n + 12] + u * B3[n];
        }
    }
    chunk_sdt[(b * NCHUNK + c) * D_INNER + d] = sdt;
#pragma unroll
    for (int n = 0; n < 16; n++)
        chunk_S[((size_t)(b * NCHUNK + c) * 16 + n) * D_INNER + d] = h[n];
}

__global__ __launch_bounds__(256) void scan2_k(
    const float* __restrict__ dtf, const bf16* __restrict__ xcb,
    const float* __restrict__ xdbl, const bf16* __restrict__ xz,
    const float* __restrict__ Alog, const float* __restrict__ Dp,
    const float* __restrict__ chunk_sdt, const float* __restrict__ chunk_S,
    bf16* __restrict__ yb)
{
    __shared__ float dt_s[CHUNK][256];
    __shared__ short xc_s[CHUNK][256];
    __shared__ float B_s[CHUNK][16];
    __shared__ float C_s[CHUNK][16];
    const int tid = threadIdx.x;
    const int d0  = blockIdx.x * 256;
    const int d   = d0 + tid;
    const int b   = blockIdx.y;
    const int c   = blockIdx.z;
    const size_t rbase = (size_t)b * SEQ + c * CHUNK;

#pragma unroll 4
    for (int t = 0; t < CHUNK; t++) {
        dt_s[t][tid] = dtf[(rbase + t) * D_INNER + d0 + tid];
        ((short*)xc_s)[t * 256 + tid] = *(const short*)&xcb[(rbase + t) * D_INNER + d0 + tid];
    }
    for (int e = tid; e < CHUNK * 16; e += 256) {
        int t = e >> 4, n = e & 15;
        B_s[t][n] = xdbl[(rbase + t) * 96 + 64 + n];
        C_s[t][n] = xdbl[(rbase + t) * 96 + 80 + n];
    }
    float A[16];
#pragma unroll
    for (int n = 0; n < 16; n++) A[n] = -__expf(Alog[(size_t)d * 16 + n]);

    // rebuild h_init from earlier chunks (c block-uniform; loads j-independent)
    float h[16] = {};
    for (int j = 0; j < c; j++) {
        float sdt = chunk_sdt[(b * NCHUNK + j) * D_INNER + d];
#pragma unroll
        for (int n = 0; n < 16; n++) {
            float S = chunk_S[((size_t)(b * NCHUNK + j) * 16 + n) * D_INNER + d];
            h[n] = __expf(sdt * A[n]) * h[n] + S;
        }
    }
    const float Dv = Dp[d];
    __syncthreads();

    for (int t = 0; t < CHUNK; t++) {
        size_t row = rbase + t;
        float dtv = dt_s[t][tid];
        bf16 xcr; short xs = xc_s[t][tid]; __builtin_memcpy(&xcr, &xs, 2);
        float xcv = bf2f(xcr);
        float u = dtv * xcv;
        floatx4 B0 = *(const floatx4*)&B_s[t][0];
        floatx4 B1 = *(const floatx4*)&B_s[t][4];
        floatx4 B2 = *(const floatx4*)&B_s[t][8];
        floatx4 B3 = *(const floatx4*)&B_s[t][12];
        floatx4 C0 = *(const floatx4*)&C_s[t][0];
        floatx4 C1 = *(const floatx4*)&C_s[t][4];
        floatx4 C2 = *(const floatx4*)&C_s[t][8];
        floatx4 C3 = *(const floatx4*)&C_s[t][12];
        float y = 0.f;
#pragma unroll
        for (int n = 0; n < 4; n++) {
            h[n]      = __expf(dtv * A[n])      * h[n]      + u * B0[n];
            h[n + 4]  = __expf(dtv * A[n + 4])  * h[n + 4]  + u * B1[n];
            h[n + 8]  = __expf(dtv * A[n + 8])  * h[n + 8]  + u * B2[n];
            h[n + 12] = __expf(dtv * A[n + 12]) * h[n + 12] + u * B3[n];
            y += h[n] * C0[n] + h[n + 4] * C1[n] + h[n + 8] * C2[n] + h[n + 12] * C3[n];
        }
        float zv = bf2f(xz[row * 4096 + 2048 + d]);
        y = (y + Dv * xcv) * (zv / (1.f + __expf(-zv)));
        yb[row * D_INNER + d] = f2bf(y);
    }
}

extern "C" void kernel_launch(void* const* d_in, const int* in_sizes, int n_in,
                              void* d_out, int out_size, void* d_ws, size_t ws_size,
                              hipStream_t stream)
{
    // ALL inputs fp32; OUTPUT IS FP32.
    const float* x    = (const float*)d_in[0];
    const float* inw  = (const float*)d_in[1];
    const float* cw   = (const float*)d_in[2];
    const float* cb   = (const float*)d_in[3];
    const float* xpw  = (const float*)d_in[4];
    const float* dtw  = (const float*)d_in[5];
    const float* dtb  = (const float*)d_in[6];
    const float* Alog = (const float*)d_in[7];
    const float* Dp   = (const float*)d_in[8];
    const float* ow   = (const float*)d_in[9];
    float* out = (float*)d_out;

    // workspace layout (~64 MB)
    char* p = (char*)d_ws;
    bf16*  xzb   = (bf16*)p;  p += (size_t)MROWS * 4096 * 2;        // 16.8 MB
    bf16*  xcb   = (bf16*)p;  p += (size_t)MROWS * D_INNER * 2;     //  8.4 MB
    float* xdblf = (float*)p; p += (size_t)MROWS * 96 * 4;          //  0.8 MB
    float* dtf   = (float*)p; p += (size_t)MROWS * D_INNER * 4;     // 16.8 MB
    bf16*  ybf   = (bf16*)p;  p += (size_t)MROWS * D_INNER * 2;     //  8.4 MB
    bf16*  xmid  = (bf16*)p;  p += (size_t)MROWS * DIM * 2;         //  4.2 MB
    float* csdt  = (float*)p; p += (size_t)BATCH * NCHUNK * D_INNER * 4;      // 0.5 MB
    float* cS    = (float*)p; p += (size_t)BATCH * NCHUNK * 16 * D_INNER * 4; // 8.4 MB

    for (int l = 0; l < 2; l++) {
        const float* inw_l = inw + (size_t)l * 2 * D_INNER * DIM;
        const float* xpw_l = xpw + (size_t)l * 96 * D_INNER;
        const float* dtw_l = dtw + (size_t)l * D_INNER * DT_RANK;
        const float* ow_l  = ow  + (size_t)l * DIM * D_INNER;
        const float* Al    = Alog + (size_t)l * D_INNER * D_STATE;

        // 1. xz = xin @ in_proj_w^T   (M=2048, N=4096, K=1024), bf16 out
        if (l == 0)
            gemm_bt<<<dim3(64, 32), 256, 0, stream>>>(
                x, 1, DIM, inw_l, 1, DIM,
                nullptr, xzb, 4096, 4096, DIM, nullptr, 0);
        else
            gemm_bt<<<dim3(64, 32), 256, 0, stream>>>(
                xmid, 0, DIM, inw_l, 1, DIM,
                nullptr, xzb, 4096, 4096, DIM, nullptr, 0);

        // 2. causal depthwise conv + bias + SiLU
        conv_silu_k<<<(MROWS * D_INNER) / 256, 256, 0, stream>>>(
            xzb, cw + (size_t)l * D_INNER * 4, cb + (size_t)l * D_INNER, xcb);

        // 3. x_dbl = xc @ x_proj_w^T   (N=96, K=2048), fp32 out
        gemm_bt<<<dim3(2, 32), 256, 0, stream>>>(
            xcb, 0, D_INNER, xpw_l, 1, D_INNER,
            xdblf, nullptr, 96, 96, D_INNER, nullptr, 0);

        // 4. dt = softplus(dt_raw @ dt_proj_w^T + dt_b)  (N=2048, K=64), fp32
        gemm_bt<<<dim3(32, 32), 256, 0, stream>>>(
            xdblf, 1, 96, dtw_l, 1, DT_RANK,
            dtf, nullptr, D_INNER, D_INNER, DT_RANK,
            dtb + (size_t)l * D_INNER, 1);

        // 5. chunk-parallel selective scan (2 stages) + gating epilogue
        scan1_k<<<dim3(D_INNER / 256, BATCH, NCHUNK), 256, 0, stream>>>(
            dtf, xcb, xdblf, Al, csdt, cS);
        scan2_k<<<dim3(D_INNER / 256, BATCH, NCHUNK), 256, 0, stream>>>(
            dtf, xcb, xdblf, xzb, Al, Dp + (size_t)l * D_INNER,
            csdt, cS, ybf);

        // 6. out = y @ out_proj_w^T   (N=1024, K=2048)
        if (l == 0)
            gemm_bt<<<dim3(16, 32), 256, 0, stream>>>(
                ybf, 0, D_INNER, ow_l, 1, D_INNER,
                nullptr, xmid, DIM, DIM, D_INNER, nullptr, 0);
        else
            gemm_bt<<<dim3(16, 32), 256, 0, stream>>>(
                ybf, 0, D_INNER, ow_l, 1, D_INNER,
                out, nullptr, DIM, DIM, D_INNER, nullptr, 0);
    }
}

// Round 9
// 495.011 us; speedup vs baseline: 3.9522x; 1.1843x over previous
//
#include <hip/hip_runtime.h>
#include <hip/hip_bf16.h>

typedef __hip_bfloat16 bf16;
typedef __attribute__((ext_vector_type(8))) short short8;
typedef __attribute__((ext_vector_type(4))) short shortx4;
typedef __attribute__((ext_vector_type(4))) float floatx4;

#define BATCH   2
#define SEQ     1024
#define DIM     1024
#define D_INNER 2048
#define D_STATE 16
#define DT_RANK 64
#define MROWS   (BATCH * SEQ)   // 2048
#define CHUNK   32
#define NCHUNK  (SEQ / CHUNK)   // 32

__device__ __forceinline__ float bf2f(bf16 x) { return __bfloat162float(x); }
__device__ __forceinline__ bf16  f2bf(float x) { return __float2bfloat16(x); }
__device__ __forceinline__ short bfbits(float x) {
    bf16 b = __float2bfloat16(x); short s; __builtin_memcpy(&s, &b, 2); return s;
}

// ---------------------------------------------------------------------------
// fp32 -> bf16 cast, 4 elements/thread.
// ---------------------------------------------------------------------------
__global__ __launch_bounds__(256) void cast_k(
    const float* __restrict__ in, short* __restrict__ o, int n4)
{
    int i = blockIdx.x * 256 + threadIdx.x;
    if (i >= n4) return;
    floatx4 v = ((const floatx4*)in)[i];
    shortx4 r;
    r.x = bfbits(v.x); r.y = bfbits(v.y); r.z = bfbits(v.z); r.w = bfbits(v.w);
    ((shortx4*)o)[i] = r;
}

// 8 contiguous elements -> short8 bf16 (fp32 converted on the fly).
__device__ __forceinline__ short8 ld8_any(const void* p, size_t eoff, int is_f32) {
    if (is_f32) {
        const float* f = (const float*)p + eoff;
        floatx4 a = *(const floatx4*)f;
        floatx4 b = *(const floatx4*)(f + 4);
        short8 r;
        r[0] = bfbits(a[0]); r[1] = bfbits(a[1]); r[2] = bfbits(a[2]); r[3] = bfbits(a[3]);
        r[4] = bfbits(b[0]); r[5] = bfbits(b[1]); r[6] = bfbits(b[2]); r[7] = bfbits(b[3]);
        return r;
    } else {
        return *(const short8*)((const bf16*)p + eoff);
    }
}

// ---------------------------------------------------------------------------
// gemm128: C[m,n] = sum_k A[m,k]*B[n,k]; A,B bf16 row-major; M,N mult of 128,
// K mult of 32. 128x128x32 tile, 256 thr = 4 waves (2x2), each wave 64x64 =
// 4x4 MFMA 16x16x32 subtiles. 64 MFMA per 16KB staged (4x density of the
// 64-tile; R8 showed that one VALU/staging-bound at MfmaUtil 10%).
// ---------------------------------------------------------------------------
__global__ __launch_bounds__(256) void gemm128(
    const bf16* __restrict__ A, int lda,
    const bf16* __restrict__ B, int ldb,
    float* __restrict__ Cf, bf16* __restrict__ Cb, int ldc, int K)
{
    __shared__ short As[128 * 32];
    __shared__ short Bs[128 * 32];
    const int tid  = threadIdx.x;
    const int wave = tid >> 6;
    const int lane = tid & 63;
    const int m0 = blockIdx.y * 128;
    const int n0 = blockIdx.x * 128;
    const int wm = (wave & 1) * 64;
    const int wn = (wave >> 1) * 64;
    const int r16  = lane & 15;
    const int quad = lane >> 4;
    const int r0 = tid >> 2;            // staging row (chunk q=tid)
    const int c0 = (tid & 3) << 3;      // staging col

    floatx4 acc[4][4] = {};

    for (int k0 = 0; k0 < K; k0 += 32) {
        short8 a0 = *(const short8*)(A + (size_t)(m0 + r0) * lda + k0 + c0);
        short8 a1 = *(const short8*)(A + (size_t)(m0 + r0 + 64) * lda + k0 + c0);
        short8 b0 = *(const short8*)(B + (size_t)(n0 + r0) * ldb + k0 + c0);
        short8 b1 = *(const short8*)(B + (size_t)(n0 + r0 + 64) * ldb + k0 + c0);
        __syncthreads();                 // previous iter's frag reads done
        *(short8*)(As + tid * 8)         = a0;   // chunk q at shorts q*8
        *(short8*)(As + (tid + 256) * 8) = a1;
        *(short8*)(Bs + tid * 8)         = b0;
        *(short8*)(Bs + (tid + 256) * 8) = b1;
        __syncthreads();
        short8 af[4], bg[4];
#pragma unroll
        for (int i = 0; i < 4; i++) {
            af[i] = *(const short8*)(As + (wm + i * 16 + r16) * 32 + quad * 8);
            bg[i] = *(const short8*)(Bs + (wn + i * 16 + r16) * 32 + quad * 8);
        }
#pragma unroll
        for (int i = 0; i < 4; i++)
#pragma unroll
            for (int j = 0; j < 4; j++)
                acc[i][j] = __builtin_amdgcn_mfma_f32_16x16x32_bf16(af[i], bg[j], acc[i][j], 0, 0, 0);
    }

#pragma unroll
    for (int i = 0; i < 4; i++)
#pragma unroll
        for (int j = 0; j < 4; j++) {
            int gm = m0 + wm + i * 16 + quad * 4;   // D row = quad*4 + r
            int gn = n0 + wn + j * 16 + r16;        // D col = r16
#pragma unroll
            for (int r = 0; r < 4; r++) {
                size_t o = (size_t)(gm + r) * ldc + gn;
                float v = acc[i][j][r];
                if (Cf) Cf[o] = v;
                if (Cb) Cb[o] = f2bf(v);
            }
        }
}

// ---------------------------------------------------------------------------
// gemm_bt (64x64x32): kept for N=96 (x_proj, with split-K via blockIdx.z)
// and K=64 (dt_proj). LDS padded [64][40] (R8: 5.2M bank-conflict cycles from
// the unpadded 64B row stride). K param = per-z-chunk K; psize = partial-C
// stride for split-K (0 / gridDim.z=1 for normal calls).
// ---------------------------------------------------------------------------
__global__ __launch_bounds__(256) void gemm_bt(
    const void* __restrict__ A, int a_f32, int lda,
    const void* __restrict__ B, int b_f32, int ldb,
    float* __restrict__ Cf, bf16* __restrict__ Cb, int ldc,
    int N, int K, size_t psize,
    const float* __restrict__ bias, int act)
{
    __shared__ short As[64][40];
    __shared__ short Bs[64][40];
    const int m0   = blockIdx.y * 64;
    const int n0   = blockIdx.x * 64;
    const int tid  = threadIdx.x;
    const int wave = tid >> 6;
    const int lane = tid & 63;
    const int srow = tid >> 2;
    const int scol = (tid & 3) << 3;
    const int r16  = lane & 15;
    const int quad = lane >> 4;
    const int kbeg = blockIdx.z * K;

    floatx4 acc[4] = {};

    for (int k0 = kbeg; k0 < kbeg + K; k0 += 32) {
        short8 av = ld8_any(A, (size_t)(m0 + srow) * lda + k0 + scol, a_f32);
        short8 bv = {};
        int gn = n0 + srow;
        if (gn < N) bv = ld8_any(B, (size_t)gn * ldb + k0 + scol, b_f32);
        *(short8*)(&As[srow][scol]) = av;
        *(short8*)(&Bs[srow][scol]) = bv;
        __syncthreads();
        short8 af = *(const short8*)(&As[wave * 16 + r16][quad * 8]);
#pragma unroll
        for (int nt = 0; nt < 4; nt++) {
            short8 bq = *(const short8*)(&Bs[nt * 16 + r16][quad * 8]);
            acc[nt] = __builtin_amdgcn_mfma_f32_16x16x32_bf16(af, bq, acc[nt], 0, 0, 0);
        }
        __syncthreads();
    }

    float* Cfp = Cf ? Cf + (size_t)blockIdx.z * psize : nullptr;
#pragma unroll
    for (int nt = 0; nt < 4; nt++) {
        int gn = n0 + nt * 16 + r16;
        if (gn >= N) continue;
        float bsv = bias ? bias[gn] : 0.f;
#pragma unroll
        for (int r = 0; r < 4; r++) {
            int gm = m0 + wave * 16 + quad * 4 + r;
            float v = acc[nt][r] + bsv;
            if (act == 1) v = (v > 20.f) ? v : log1pf(__expf(v));  // softplus
            size_t o = (size_t)gm * ldc + gn;
            if (Cfp) Cfp[o] = v;
            if (Cb) Cb[o] = f2bf(v);
        }
    }
}

// sum 4 split-K partials -> fp32
__global__ __launch_bounds__(256) void reduce4_k(
    const float* __restrict__ part, float* __restrict__ o, int n, size_t psize)
{
    int i = blockIdx.x * 256 + threadIdx.x;
    if (i < n)
        o[i] = part[i] + part[i + psize] + part[i + 2 * psize] + part[i + 3 * psize];
}

// ---------------------------------------------------------------------------
// Depthwise causal conv (4 taps) + bias + SiLU over xi = xz[:, :, 0:2048].
// ---------------------------------------------------------------------------
__global__ __launch_bounds__(256) void conv_silu_k(
    const bf16* __restrict__ xz, const float* __restrict__ cw,
    const float* __restrict__ cb, bf16* __restrict__ xcb)
{
    int idx = blockIdx.x * 256 + threadIdx.x;      // bt*2048 + d
    int d   = idx & (D_INNER - 1);
    int bt  = idx >> 11;
    int t   = bt & (SEQ - 1);
    float s = cb[d];
#pragma unroll
    for (int j = 0; j < 4; j++) {
        int tt = t - 3 + j;
        if (tt >= 0) s += cw[d * 4 + j] * bf2f(xz[(size_t)(bt - 3 + j) * 4096 + d]);
    }
    float sig = 1.f / (1.f + __expf(-s));
    xcb[idx] = f2bf(s * sig);
}

// ---------------------------------------------------------------------------
// Selective scan (v4, validated R8): chunk-parallel, channel-per-thread,
// bulk LDS staging. See R7/R8 notes.
// ---------------------------------------------------------------------------
__global__ __launch_bounds__(256) void scan1_k(
    const float* __restrict__ dtf, const bf16* __restrict__ xcb,
    const float* __restrict__ xdbl, const float* __restrict__ Alog,
    float* __restrict__ chunk_sdt, float* __restrict__ chunk_S)
{
    __shared__ float dt_s[CHUNK][256];
    __shared__ short xc_s[CHUNK][256];
    __shared__ float B_s[CHUNK][16];
    const int tid = threadIdx.x;
    const int d0  = blockIdx.x * 256;
    const int d   = d0 + tid;
    const int b   = blockIdx.y;
    const int c   = blockIdx.z;
    const size_t rbase = (size_t)b * SEQ + c * CHUNK;

#pragma unroll 4
    for (int t = 0; t < CHUNK; t++) {
        dt_s[t][tid] = dtf[(rbase + t) * D_INNER + d0 + tid];
        ((short*)xc_s)[t * 256 + tid] = *(const short*)&xcb[(rbase + t) * D_INNER + d0 + tid];
    }
    for (int e = tid; e < CHUNK * 16; e += 256) {
        int t = e >> 4, n = e & 15;
        B_s[t][n] = xdbl[(rbase + t) * 96 + 64 + n];
    }
    float A[16];
#pragma unroll
    for (int n = 0; n < 16; n++) A[n] = -__expf(Alog[(size_t)d * 16 + n]);
    float h[16] = {};
    float sdt = 0.f;
    __syncthreads();

    for (int t = 0; t < CHUNK; t++) {
        float dtv = dt_s[t][tid];
        bf16 xcr; short xs = xc_s[t][tid]; __builtin_memcpy(&xcr, &xs, 2);
        float u = dtv * bf2f(xcr);
        sdt += dtv;
        floatx4 B0 = *(const floatx4*)&B_s[t][0];
        floatx4 B1 = *(const floatx4*)&B_s[t][4];
        floatx4 B2 = *(const floatx4*)&B_s[t][8];
        floatx4 B3 = *(const floatx4*)&B_s[t][12];
#pragma unroll
        for (int n = 0; n < 4; n++) {
            h[n]      = __expf(dtv * A[n])      * h[n]      + u * B0[n];
            h[n + 4]  = __expf(dtv * A[n + 4])  * h[n + 4]  + u * B1[n];
            h[n + 8]  = __expf(dtv * A[n + 8])  * h[n + 8]  + u * B2[n];
            h[n + 12] = __expf(dtv * A[n + 12]) * h[n + 12] + u * B3[n];
        }
    }
    chunk_sdt[(b * NCHUNK + c) * D_INNER + d] = sdt;
#pragma unroll
    for (int n = 0; n < 16; n++)
        chunk_S[((size_t)(b * NCHUNK + c) * 16 + n) * D_INNER + d] = h[n];
}

__global__ __launch_bounds__(256) void scan2_k(
    const float* __restrict__ dtf, const bf16* __restrict__ xcb,
    const float* __restrict__ xdbl, const bf16* __restrict__ xz,
    const float* __restrict__ Alog, const float* __restrict__ Dp,
    const float* __restrict__ chunk_sdt, const float* __restrict__ chunk_S,
    bf16* __restrict__ yb)
{
    __shared__ float dt_s[CHUNK][256];
    __shared__ short xc_s[CHUNK][256];
    __shared__ float B_s[CHUNK][16];
    __shared__ float C_s[CHUNK][16];
    const int tid = threadIdx.x;
    const int d0  = blockIdx.x * 256;
    const int d   = d0 + tid;
    const int b   = blockIdx.y;
    const int c   = blockIdx.z;
    const size_t rbase = (size_t)b * SEQ + c * CHUNK;

#pragma unroll 4
    for (int t = 0; t < CHUNK; t++) {
        dt_s[t][tid] = dtf[(rbase + t) * D_INNER + d0 + tid];
        ((short*)xc_s)[t * 256 + tid] = *(const short*)&xcb[(rbase + t) * D_INNER + d0 + tid];
    }
    for (int e = tid; e < CHUNK * 16; e += 256) {
        int t = e >> 4, n = e & 15;
        B_s[t][n] = xdbl[(rbase + t) * 96 + 64 + n];
        C_s[t][n] = xdbl[(rbase + t) * 96 + 80 + n];
    }
    float A[16];
#pragma unroll
    for (int n = 0; n < 16; n++) A[n] = -__expf(Alog[(size_t)d * 16 + n]);

    float h[16] = {};
    for (int j = 0; j < c; j++) {
        float sdt = chunk_sdt[(b * NCHUNK + j) * D_INNER + d];
#pragma unroll
        for (int n = 0; n < 16; n++) {
            float S = chunk_S[((size_t)(b * NCHUNK + j) * 16 + n) * D_INNER + d];
            h[n] = __expf(sdt * A[n]) * h[n] + S;
        }
    }
    const float Dv = Dp[d];
    __syncthreads();

    for (int t = 0; t < CHUNK; t++) {
        size_t row = rbase + t;
        float dtv = dt_s[t][tid];
        bf16 xcr; short xs = xc_s[t][tid]; __builtin_memcpy(&xcr, &xs, 2);
        float xcv = bf2f(xcr);
        float u = dtv * xcv;
        floatx4 B0 = *(const floatx4*)&B_s[t][0];
        floatx4 B1 = *(const floatx4*)&B_s[t][4];
        floatx4 B2 = *(const floatx4*)&B_s[t][8];
        floatx4 B3 = *(const floatx4*)&B_s[t][12];
        floatx4 C0 = *(const floatx4*)&C_s[t][0];
        floatx4 C1 = *(const floatx4*)&C_s[t][4];
        floatx4 C2 = *(const floatx4*)&C_s[t][8];
        floatx4 C3 = *(const floatx4*)&C_s[t][12];
        float y = 0.f;
#pragma unroll
        for (int n = 0; n < 4; n++) {
            h[n]      = __expf(dtv * A[n])      * h[n]      + u * B0[n];
            h[n + 4]  = __expf(dtv * A[n + 4])  * h[n + 4]  + u * B1[n];
            h[n + 8]  = __expf(dtv * A[n + 8])  * h[n + 8]  + u * B2[n];
            h[n + 12] = __expf(dtv * A[n + 12]) * h[n + 12] + u * B3[n];
            y += h[n] * C0[n] + h[n + 4] * C1[n] + h[n + 8] * C2[n] + h[n + 12] * C3[n];
        }
        float zv = bf2f(xz[row * 4096 + 2048 + d]);
        y = (y + Dv * xcv) * (zv / (1.f + __expf(-zv)));
        yb[row * D_INNER + d] = f2bf(y);
    }
}

extern "C" void kernel_launch(void* const* d_in, const int* in_sizes, int n_in,
                              void* d_out, int out_size, void* d_ws, size_t ws_size,
                              hipStream_t stream)
{
    // ALL inputs fp32; OUTPUT IS FP32.
    const float* x    = (const float*)d_in[0];
    const float* inw  = (const float*)d_in[1];
    const float* cw   = (const float*)d_in[2];
    const float* cb   = (const float*)d_in[3];
    const float* xpw  = (const float*)d_in[4];
    const float* dtw  = (const float*)d_in[5];
    const float* dtb  = (const float*)d_in[6];
    const float* Alog = (const float*)d_in[7];
    const float* Dp   = (const float*)d_in[8];
    const float* ow   = (const float*)d_in[9];
    float* out = (float*)d_out;

    // workspace layout (~84 MB; R1 empirically proved >=87 MB backed)
    char* p = (char*)d_ws;
    bf16*  xzb   = (bf16*)p;  p += (size_t)MROWS * 4096 * 2;        // 16.8 MB
    bf16*  xcb   = (bf16*)p;  p += (size_t)MROWS * D_INNER * 2;     //  8.4 MB
    float* xdblf = (float*)p; p += (size_t)MROWS * 96 * 4;          //  0.8 MB
    float* dtf   = (float*)p; p += (size_t)MROWS * D_INNER * 4;     // 16.8 MB
    bf16*  ybf   = (bf16*)p;  p += (size_t)MROWS * D_INNER * 2;     //  8.4 MB
    bf16*  xmid  = (bf16*)p;  p += (size_t)MROWS * DIM * 2;         //  4.2 MB
    float* csdt  = (float*)p; p += (size_t)BATCH * NCHUNK * D_INNER * 4;      // 0.5 MB
    float* cS    = (float*)p; p += (size_t)BATCH * NCHUNK * 16 * D_INNER * 4; // 8.4 MB
    bf16*  xb    = (bf16*)p;  p += (size_t)MROWS * DIM * 2;         //  4.2 MB
    bf16*  inwb  = (bf16*)p;  p += (size_t)2 * D_INNER * DIM * 2;   //  8.4 MB (one layer)
    bf16*  owb   = (bf16*)p;  p += (size_t)DIM * D_INNER * 2;       //  4.2 MB (one layer)
    float* xprt  = (float*)p; p += (size_t)4 * MROWS * 96 * 4;      //  3.1 MB

    const size_t xp_psize = (size_t)MROWS * 96;

    // input cast (once)
    cast_k<<<(MROWS * DIM / 4 + 255) / 256, 256, 0, stream>>>(x, (short*)xb, MROWS * DIM / 4);

    for (int l = 0; l < 2; l++) {
        const float* xpw_l = xpw + (size_t)l * 96 * D_INNER;
        const float* dtw_l = dtw + (size_t)l * D_INNER * DT_RANK;
        const float* Al    = Alog + (size_t)l * D_INNER * D_STATE;

        // 0. cast this layer's big weights to bf16
        cast_k<<<(2 * D_INNER * DIM / 4 + 255) / 256, 256, 0, stream>>>(
            inw + (size_t)l * 2 * D_INNER * DIM, (short*)inwb, 2 * D_INNER * DIM / 4);
        cast_k<<<(DIM * D_INNER / 4 + 255) / 256, 256, 0, stream>>>(
            ow + (size_t)l * DIM * D_INNER, (short*)owb, DIM * D_INNER / 4);

        // 1. xz = xin @ in_proj_w^T   (M=2048, N=4096, K=1024), bf16 out
        gemm128<<<dim3(32, 16), 256, 0, stream>>>(
            (l == 0) ? xb : xmid, DIM, inwb, DIM,
            nullptr, xzb, 4096, DIM);

        // 2. causal depthwise conv + bias + SiLU
        conv_silu_k<<<(MROWS * D_INNER) / 256, 256, 0, stream>>>(
            xzb, cw + (size_t)l * D_INNER * 4, cb + (size_t)l * D_INNER, xcb);

        // 3. x_dbl = xc @ x_proj_w^T   (N=96, K=2048), split-K=4 + reduce
        gemm_bt<<<dim3(2, 32, 4), 256, 0, stream>>>(
            xcb, 0, D_INNER, xpw_l, 1, D_INNER,
            xprt, nullptr, 96, 96, 512, xp_psize, nullptr, 0);
        reduce4_k<<<(MROWS * 96 + 255) / 256, 256, 0, stream>>>(
            xprt, xdblf, MROWS * 96, xp_psize);

        // 4. dt = softplus(dt_raw @ dt_proj_w^T + dt_b)  (N=2048, K=64), fp32
        gemm_bt<<<dim3(32, 32), 256, 0, stream>>>(
            xdblf, 1, 96, dtw_l, 1, DT_RANK,
            dtf, nullptr, D_INNER, D_INNER, DT_RANK, 0,
            dtb + (size_t)l * D_INNER, 1);

        // 5. chunk-parallel selective scan (2 stages) + gating epilogue
        scan1_k<<<dim3(D_INNER / 256, BATCH, NCHUNK), 256, 0, stream>>>(
            dtf, xcb, xdblf, Al, csdt, cS);
        scan2_k<<<dim3(D_INNER / 256, BATCH, NCHUNK), 256, 0, stream>>>(
            dtf, xcb, xdblf, xzb, Al, Dp + (size_t)l * D_INNER,
            csdt, cS, ybf);

        // 6. out = y @ out_proj_w^T   (N=1024, K=2048)
        if (l == 0)
            gemm128<<<dim3(8, 16), 256, 0, stream>>>(
                ybf, D_INNER, owb, D_INNER,
                nullptr, xmid, DIM, D_INNER);
        else
            gemm128<<<dim3(8, 16), 256, 0, stream>>>(
                ybf, D_INNER, owb, D_INNER,
                out, nullptr, DIM, D_INNER);
    }
}

// Round 10
// 473.330 us; speedup vs baseline: 4.1332x; 1.0458x over previous
//
#include <hip/hip_runtime.h>
#include <hip/hip_bf16.h>

typedef __hip_bfloat16 bf16;
typedef __attribute__((ext_vector_type(8))) short short8;
typedef __attribute__((ext_vector_type(4))) short shortx4;
typedef __attribute__((ext_vector_type(4))) float floatx4;

#define BATCH   2
#define SEQ     1024
#define DIM     1024
#define D_INNER 2048
#define D_STATE 16
#define DT_RANK 64
#define MROWS   (BATCH * SEQ)   // 2048
#define CHUNK   32
#define NCHUNK  (SEQ / CHUNK)   // 32

__device__ __forceinline__ float bf2f(bf16 x) { return __bfloat162float(x); }
__device__ __forceinline__ bf16  f2bf(float x) { return __float2bfloat16(x); }
__device__ __forceinline__ short bfbits(float x) {
    bf16 b = __float2bfloat16(x); short s; __builtin_memcpy(&s, &b, 2); return s;
}

// async global->LDS, 16B per lane. LDS dest must be wave-uniform base +
// lane*16 (m104/m108); our chunk layouts satisfy this by construction.
__device__ __forceinline__ void ld_lds16(const void* g, void* l) {
    __builtin_amdgcn_global_load_lds(
        (const __attribute__((address_space(1))) void*)g,
        (__attribute__((address_space(3))) void*)l, 16, 0, 0);
}

// ---------------------------------------------------------------------------
// fp32 -> bf16 cast, 4 elements/thread.
// ---------------------------------------------------------------------------
__global__ __launch_bounds__(256) void cast_k(
    const float* __restrict__ in, short* __restrict__ o, int n4)
{
    int i = blockIdx.x * 256 + threadIdx.x;
    if (i >= n4) return;
    floatx4 v = ((const floatx4*)in)[i];
    shortx4 r;
    r.x = bfbits(v.x); r.y = bfbits(v.y); r.z = bfbits(v.z); r.w = bfbits(v.w);
    ((shortx4*)o)[i] = r;
}

// 8 contiguous elements -> short8 bf16 (fp32 converted on the fly).
__device__ __forceinline__ short8 ld8_any(const void* p, size_t eoff, int is_f32) {
    if (is_f32) {
        const float* f = (const float*)p + eoff;
        floatx4 a = *(const floatx4*)f;
        floatx4 b = *(const floatx4*)(f + 4);
        short8 r;
        r[0] = bfbits(a[0]); r[1] = bfbits(a[1]); r[2] = bfbits(a[2]); r[3] = bfbits(a[3]);
        r[4] = bfbits(b[0]); r[5] = bfbits(b[1]); r[6] = bfbits(b[2]); r[7] = bfbits(b[3]);
        return r;
    } else {
        return *(const short8*)((const bf16*)p + eoff);
    }
}

// ---------------------------------------------------------------------------
// gemm128: C[m,n] = sum_k A[m,k]*B[n,k]; A,B bf16 row-major; M,N mult of 128.
// 128x128x32 tile, 256 thr = 4 waves (2x2), each wave 64x64 = 4x4 MFMA.
// R10: staging via global_load_lds width=16 (m93->m97 ladder step; kills the
// VGPR round-trip that kept VALUBusy>MfmaUtil in R9), split-K via blockIdx.z
// (R9: out_proj at 128 blocks left half the CUs idle, 56.6us).
// ---------------------------------------------------------------------------
__global__ __launch_bounds__(256) void gemm128(
    const bf16* __restrict__ A, int lda,
    const bf16* __restrict__ B, int ldb,
    float* __restrict__ Cf, bf16* __restrict__ Cb, int ldc,
    int kchunk, size_t psize)
{
    __shared__ short As[128 * 32];
    __shared__ short Bs[128 * 32];
    const int tid  = threadIdx.x;
    const int wave = tid >> 6;
    const int lane = tid & 63;
    const int m0 = blockIdx.y * 128;
    const int n0 = blockIdx.x * 128;
    const int wm = (wave & 1) * 64;
    const int wn = (wave >> 1) * 64;
    const int r16  = lane & 15;
    const int quad = lane >> 4;
    const int r0 = tid >> 2;            // staging row (chunk q=tid)
    const int c0 = (tid & 3) << 3;      // staging col (elements)
    const int kbeg = blockIdx.z * kchunk;

    floatx4 acc[4][4] = {};

    for (int k0 = kbeg; k0 < kbeg + kchunk; k0 += 32) {
        __syncthreads();                 // prev iter's frag reads done
        ld_lds16(A + (size_t)(m0 + r0) * lda + k0 + c0,      As + tid * 8);
        ld_lds16(A + (size_t)(m0 + r0 + 64) * lda + k0 + c0, As + (tid + 256) * 8);
        ld_lds16(B + (size_t)(n0 + r0) * ldb + k0 + c0,      Bs + tid * 8);
        ld_lds16(B + (size_t)(n0 + r0 + 64) * ldb + k0 + c0, Bs + (tid + 256) * 8);
        __syncthreads();                 // drains vmcnt(0) (m97 structure)
        short8 af[4], bg[4];
#pragma unroll
        for (int i = 0; i < 4; i++) {
            af[i] = *(const short8*)(As + (wm + i * 16 + r16) * 32 + quad * 8);
            bg[i] = *(const short8*)(Bs + (wn + i * 16 + r16) * 32 + quad * 8);
        }
#pragma unroll
        for (int i = 0; i < 4; i++)
#pragma unroll
            for (int j = 0; j < 4; j++)
                acc[i][j] = __builtin_amdgcn_mfma_f32_16x16x32_bf16(af[i], bg[j], acc[i][j], 0, 0, 0);
    }

    float* Cfp = Cf ? Cf + (size_t)blockIdx.z * psize : nullptr;
#pragma unroll
    for (int i = 0; i < 4; i++)
#pragma unroll
        for (int j = 0; j < 4; j++) {
            int gm = m0 + wm + i * 16 + quad * 4;   // D row = quad*4 + r
            int gn = n0 + wn + j * 16 + r16;        // D col = r16
#pragma unroll
            for (int r = 0; r < 4; r++) {
                size_t o = (size_t)(gm + r) * ldc + gn;
                float v = acc[i][j][r];
                if (Cfp) Cfp[o] = v;
                if (Cb) Cb[o] = f2bf(v);
            }
        }
}

// ---------------------------------------------------------------------------
// gemm_bt (64x64x32): kept for N=96 (x_proj, split-K via blockIdx.z) and
// K=64 (dt_proj). LDS padded [64][40].
// ---------------------------------------------------------------------------
__global__ __launch_bounds__(256) void gemm_bt(
    const void* __restrict__ A, int a_f32, int lda,
    const void* __restrict__ B, int b_f32, int ldb,
    float* __restrict__ Cf, bf16* __restrict__ Cb, int ldc,
    int N, int K, size_t psize,
    const float* __restrict__ bias, int act)
{
    __shared__ short As[64][40];
    __shared__ short Bs[64][40];
    const int m0   = blockIdx.y * 64;
    const int n0   = blockIdx.x * 64;
    const int tid  = threadIdx.x;
    const int wave = tid >> 6;
    const int lane = tid & 63;
    const int srow = tid >> 2;
    const int scol = (tid & 3) << 3;
    const int r16  = lane & 15;
    const int quad = lane >> 4;
    const int kbeg = blockIdx.z * K;

    floatx4 acc[4] = {};

    for (int k0 = kbeg; k0 < kbeg + K; k0 += 32) {
        short8 av = ld8_any(A, (size_t)(m0 + srow) * lda + k0 + scol, a_f32);
        short8 bv = {};
        int gn = n0 + srow;
        if (gn < N) bv = ld8_any(B, (size_t)gn * ldb + k0 + scol, b_f32);
        *(short8*)(&As[srow][scol]) = av;
        *(short8*)(&Bs[srow][scol]) = bv;
        __syncthreads();
        short8 af = *(const short8*)(&As[wave * 16 + r16][quad * 8]);
#pragma unroll
        for (int nt = 0; nt < 4; nt++) {
            short8 bq = *(const short8*)(&Bs[nt * 16 + r16][quad * 8]);
            acc[nt] = __builtin_amdgcn_mfma_f32_16x16x32_bf16(af, bq, acc[nt], 0, 0, 0);
        }
        __syncthreads();
    }

    float* Cfp = Cf ? Cf + (size_t)blockIdx.z * psize : nullptr;
#pragma unroll
    for (int nt = 0; nt < 4; nt++) {
        int gn = n0 + nt * 16 + r16;
        if (gn >= N) continue;
        float bsv = bias ? bias[gn] : 0.f;
#pragma unroll
        for (int r = 0; r < 4; r++) {
            int gm = m0 + wave * 16 + quad * 4 + r;
            float v = acc[nt][r] + bsv;
            if (act == 1) v = (v > 20.f) ? v : log1pf(__expf(v));  // softplus
            size_t o = (size_t)gm * ldc + gn;
            if (Cfp) Cfp[o] = v;
            if (Cb) Cb[o] = f2bf(v);
        }
    }
}

// sum 4 split-K partials -> fp32
__global__ __launch_bounds__(256) void reduce4_k(
    const float* __restrict__ part, float* __restrict__ o, int n, size_t psize)
{
    int i = blockIdx.x * 256 + threadIdx.x;
    if (i < n)
        o[i] = part[i] + part[i + psize] + part[i + 2 * psize] + part[i + 3 * psize];
}

// sum 2 split-K partials -> fp32 and/or bf16
__global__ __launch_bounds__(256) void reduce2_k(
    const float* __restrict__ part, size_t psize, int n,
    float* __restrict__ of, bf16* __restrict__ ob)
{
    int i = blockIdx.x * 256 + threadIdx.x;
    if (i >= n) return;
    float v = part[i] + part[i + psize];
    if (of) of[i] = v;
    if (ob) ob[i] = f2bf(v);
}

// ---------------------------------------------------------------------------
// Depthwise causal conv (4 taps) + bias + SiLU over xi = xz[:, :, 0:2048].
// ---------------------------------------------------------------------------
__global__ __launch_bounds__(256) void conv_silu_k(
    const bf16* __restrict__ xz, const float* __restrict__ cw,
    const float* __restrict__ cb, bf16* __restrict__ xcb)
{
    int idx = blockIdx.x * 256 + threadIdx.x;      // bt*2048 + d
    int d   = idx & (D_INNER - 1);
    int bt  = idx >> 11;
    int t   = bt & (SEQ - 1);
    float s = cb[d];
#pragma unroll
    for (int j = 0; j < 4; j++) {
        int tt = t - 3 + j;
        if (tt >= 0) s += cw[d * 4 + j] * bf2f(xz[(size_t)(bt - 3 + j) * 4096 + d]);
    }
    float sig = 1.f / (1.f + __expf(-s));
    xcb[idx] = f2bf(s * sig);
}

// ---------------------------------------------------------------------------
// Selective scan (v4, validated R8): chunk-parallel, channel-per-thread,
// bulk LDS staging.
// ---------------------------------------------------------------------------
__global__ __launch_bounds__(256) void scan1_k(
    const float* __restrict__ dtf, const bf16* __restrict__ xcb,
    const float* __restrict__ xdbl, const float* __restrict__ Alog,
    float* __restrict__ chunk_sdt, float* __restrict__ chunk_S)
{
    __shared__ float dt_s[CHUNK][256];
    __shared__ short xc_s[CHUNK][256];
    __shared__ float B_s[CHUNK][16];
    const int tid = threadIdx.x;
    const int d0  = blockIdx.x * 256;
    const int d   = d0 + tid;
    const int b   = blockIdx.y;
    const int c   = blockIdx.z;
    const size_t rbase = (size_t)b * SEQ + c * CHUNK;

#pragma unroll 4
    for (int t = 0; t < CHUNK; t++) {
        dt_s[t][tid] = dtf[(rbase + t) * D_INNER + d0 + tid];
        ((short*)xc_s)[t * 256 + tid] = *(const short*)&xcb[(rbase + t) * D_INNER + d0 + tid];
    }
    for (int e = tid; e < CHUNK * 16; e += 256) {
        int t = e >> 4, n = e & 15;
        B_s[t][n] = xdbl[(rbase + t) * 96 + 64 + n];
    }
    float A[16];
#pragma unroll
    for (int n = 0; n < 16; n++) A[n] = -__expf(Alog[(size_t)d * 16 + n]);
    float h[16] = {};
    float sdt = 0.f;
    __syncthreads();

    for (int t = 0; t < CHUNK; t++) {
        float dtv = dt_s[t][tid];
        bf16 xcr; short xs = xc_s[t][tid]; __builtin_memcpy(&xcr, &xs, 2);
        float u = dtv * bf2f(xcr);
        sdt += dtv;
        floatx4 B0 = *(const floatx4*)&B_s[t][0];
        floatx4 B1 = *(const floatx4*)&B_s[t][4];
        floatx4 B2 = *(const floatx4*)&B_s[t][8];
        floatx4 B3 = *(const floatx4*)&B_s[t][12];
#pragma unroll
        for (int n = 0; n < 4; n++) {
            h[n]      = __expf(dtv * A[n])      * h[n]      + u * B0[n];
            h[n + 4]  = __expf(dtv * A[n + 4])  * h[n + 4]  + u * B1[n];
            h[n + 8]  = __expf(dtv * A[n + 8])  * h[n + 8]  + u * B2[n];
            h[n + 12] = __expf(dtv * A[n + 12]) * h[n + 12] + u * B3[n];
        }
    }
    chunk_sdt[(b * NCHUNK + c) * D_INNER + d] = sdt;
#pragma unroll
    for (int n = 0; n < 16; n++)
        chunk_S[((size_t)(b * NCHUNK + c) * 16 + n) * D_INNER + d] = h[n];
}

__global__ __launch_bounds__(256) void scan2_k(
    const float* __restrict__ dtf, const bf16* __restrict__ xcb,
    const float* __restrict__ xdbl, const bf16* __restrict__ xz,
    const float* __restrict__ Alog, const float* __restrict__ Dp,
    const float* __restrict__ chunk_sdt, const float* __restrict__ chunk_S,
    bf16* __restrict__ yb)
{
    __shared__ float dt_s[CHUNK][256];
    __shared__ short xc_s[CHUNK][256];
    __shared__ float B_s[CHUNK][16];
    __shared__ float C_s[CHUNK][16];
    const int tid = threadIdx.x;
    const int d0  = blockIdx.x * 256;
    const int d   = d0 + tid;
    const int b   = blockIdx.y;
    const int c   = blockIdx.z;
    const size_t rbase = (size_t)b * SEQ + c * CHUNK;

#pragma unroll 4
    for (int t = 0; t < CHUNK; t++) {
        dt_s[t][tid] = dtf[(rbase + t) * D_INNER + d0 + tid];
        ((short*)xc_s)[t * 256 + tid] = *(const short*)&xcb[(rbase + t) * D_INNER + d0 + tid];
    }
    for (int e = tid; e < CHUNK * 16; e += 256) {
        int t = e >> 4, n = e & 15;
        B_s[t][n] = xdbl[(rbase + t) * 96 + 64 + n];
        C_s[t][n] = xdbl[(rbase + t) * 96 + 80 + n];
    }
    float A[16];
#pragma unroll
    for (int n = 0; n < 16; n++) A[n] = -__expf(Alog[(size_t)d * 16 + n]);

    float h[16] = {};
    for (int j = 0; j < c; j++) {
        float sdt = chunk_sdt[(b * NCHUNK + j) * D_INNER + d];
#pragma unroll
        for (int n = 0; n < 16; n++) {
            float S = chunk_S[((size_t)(b * NCHUNK + j) * 16 + n) * D_INNER + d];
            h[n] = __expf(sdt * A[n]) * h[n] + S;
        }
    }
    const float Dv = Dp[d];
    __syncthreads();

    for (int t = 0; t < CHUNK; t++) {
        size_t row = rbase + t;
        float dtv = dt_s[t][tid];
        bf16 xcr; short xs = xc_s[t][tid]; __builtin_memcpy(&xcr, &xs, 2);
        float xcv = bf2f(xcr);
        float u = dtv * xcv;
        floatx4 B0 = *(const floatx4*)&B_s[t][0];
        floatx4 B1 = *(const floatx4*)&B_s[t][4];
        floatx4 B2 = *(const floatx4*)&B_s[t][8];
        floatx4 B3 = *(const floatx4*)&B_s[t][12];
        floatx4 C0 = *(const floatx4*)&C_s[t][0];
        floatx4 C1 = *(const floatx4*)&C_s[t][4];
        floatx4 C2 = *(const floatx4*)&C_s[t][8];
        floatx4 C3 = *(const floatx4*)&C_s[t][12];
        float y = 0.f;
#pragma unroll
        for (int n = 0; n < 4; n++) {
            h[n]      = __expf(dtv * A[n])      * h[n]      + u * B0[n];
            h[n + 4]  = __expf(dtv * A[n + 4])  * h[n + 4]  + u * B1[n];
            h[n + 8]  = __expf(dtv * A[n + 8])  * h[n + 8]  + u * B2[n];
            h[n + 12] = __expf(dtv * A[n + 12]) * h[n + 12] + u * B3[n];
            y += h[n] * C0[n] + h[n + 4] * C1[n] + h[n + 8] * C2[n] + h[n + 12] * C3[n];
        }
        float zv = bf2f(xz[row * 4096 + 2048 + d]);
        y = (y + Dv * xcv) * (zv / (1.f + __expf(-zv)));
        yb[row * D_INNER + d] = f2bf(y);
    }
}

extern "C" void kernel_launch(void* const* d_in, const int* in_sizes, int n_in,
                              void* d_out, int out_size, void* d_ws, size_t ws_size,
                              hipStream_t stream)
{
    // ALL inputs fp32; OUTPUT IS FP32.
    const float* x    = (const float*)d_in[0];
    const float* inw  = (const float*)d_in[1];
    const float* cw   = (const float*)d_in[2];
    const float* cb   = (const float*)d_in[3];
    const float* xpw  = (const float*)d_in[4];
    const float* dtw  = (const float*)d_in[5];
    const float* dtb  = (const float*)d_in[6];
    const float* Alog = (const float*)d_in[7];
    const float* Dp   = (const float*)d_in[8];
    const float* ow   = (const float*)d_in[9];
    float* out = (float*)d_out;

    // workspace layout (~84 MB; R1 empirically proved >=89 MB backed)
    char* p = (char*)d_ws;
    bf16*  xzb   = (bf16*)p;  p += (size_t)MROWS * 4096 * 2;        // 16.8 MB
    bf16*  xcb   = (bf16*)p;  p += (size_t)MROWS * D_INNER * 2;     //  8.4 MB
    float* xdblf = (float*)p; p += (size_t)MROWS * 96 * 4;          //  0.8 MB
    float* dtf   = (float*)p; p += (size_t)MROWS * D_INNER * 4;     // 16.8 MB
    bf16*  ybf   = (bf16*)p;  p += (size_t)MROWS * D_INNER * 2;     //  8.4 MB
    bf16*  xmid  = (bf16*)p;  p += (size_t)MROWS * DIM * 2;         //  4.2 MB
    float* csdt  = (float*)p; p += (size_t)BATCH * NCHUNK * D_INNER * 4;      // 0.5 MB
    float* cS    = (float*)p; p += (size_t)BATCH * NCHUNK * 16 * D_INNER * 4; // 8.4 MB
    bf16*  xb    = (bf16*)p;  p += (size_t)MROWS * DIM * 2;         //  4.2 MB
    bf16*  inwb  = (bf16*)p;  p += (size_t)2 * D_INNER * DIM * 2;   //  8.4 MB (one layer)
    bf16*  owb   = (bf16*)p;  p += (size_t)DIM * D_INNER * 2;       //  4.2 MB (one layer)
    float* xprt  = (float*)p; p += (size_t)4 * MROWS * 96 * 4;      //  3.1 MB

    const size_t xp_psize = (size_t)MROWS * 96;
    const size_t op_psize = (size_t)MROWS * DIM;   // out_proj split-K partial
    float* outp = dtf;   // dtf dead after scans; 2048*2048 fp32 = 2 partials exactly

    // input cast (once)
    cast_k<<<(MROWS * DIM / 4 + 255) / 256, 256, 0, stream>>>(x, (short*)xb, MROWS * DIM / 4);

    for (int l = 0; l < 2; l++) {
        const float* xpw_l = xpw + (size_t)l * 96 * D_INNER;
        const float* dtw_l = dtw + (size_t)l * D_INNER * DT_RANK;
        const float* Al    = Alog + (size_t)l * D_INNER * D_STATE;

        // 0. cast this layer's big weights to bf16
        cast_k<<<(2 * D_INNER * DIM / 4 + 255) / 256, 256, 0, stream>>>(
            inw + (size_t)l * 2 * D_INNER * DIM, (short*)inwb, 2 * D_INNER * DIM / 4);
        cast_k<<<(DIM * D_INNER / 4 + 255) / 256, 256, 0, stream>>>(
            ow + (size_t)l * DIM * D_INNER, (short*)owb, DIM * D_INNER / 4);

        // 1. xz = xin @ in_proj_w^T   (M=2048, N=4096, K=1024), bf16 out
        gemm128<<<dim3(32, 16, 1), 256, 0, stream>>>(
            (l == 0) ? xb : xmid, DIM, inwb, DIM,
            nullptr, xzb, 4096, DIM, 0);

        // 2. causal depthwise conv + bias + SiLU
        conv_silu_k<<<(MROWS * D_INNER) / 256, 256, 0, stream>>>(
            xzb, cw + (size_t)l * D_INNER * 4, cb + (size_t)l * D_INNER, xcb);

        // 3. x_dbl = xc @ x_proj_w^T   (N=96, K=2048), split-K=4 + reduce
        gemm_bt<<<dim3(2, 32, 4), 256, 0, stream>>>(
            xcb, 0, D_INNER, xpw_l, 1, D_INNER,
            xprt, nullptr, 96, 96, 512, xp_psize, nullptr, 0);
        reduce4_k<<<(MROWS * 96 + 255) / 256, 256, 0, stream>>>(
            xprt, xdblf, MROWS * 96, xp_psize);

        // 4. dt = softplus(dt_raw @ dt_proj_w^T + dt_b)  (N=2048, K=64), fp32
        gemm_bt<<<dim3(32, 32), 256, 0, stream>>>(
            xdblf, 1, 96, dtw_l, 1, DT_RANK,
            dtf, nullptr, D_INNER, D_INNER, DT_RANK, 0,
            dtb + (size_t)l * D_INNER, 1);

        // 5. chunk-parallel selective scan (2 stages) + gating epilogue
        scan1_k<<<dim3(D_INNER / 256, BATCH, NCHUNK), 256, 0, stream>>>(
            dtf, xcb, xdblf, Al, csdt, cS);
        scan2_k<<<dim3(D_INNER / 256, BATCH, NCHUNK), 256, 0, stream>>>(
            dtf, xcb, xdblf, xzb, Al, Dp + (size_t)l * D_INNER,
            csdt, cS, ybf);

        // 6. out = y @ out_proj_w^T   (N=1024, K=2048), split-K=2 into dtf
        //    region (dead after scans), then reduce to xmid(bf16)/out(fp32)
        gemm128<<<dim3(8, 16, 2), 256, 0, stream>>>(
            ybf, D_INNER, owb, D_INNER,
            outp, nullptr, DIM, D_INNER / 2, op_psize);
        reduce2_k<<<(MROWS * DIM + 255) / 256, 256, 0, stream>>>(
            outp, op_psize, MROWS * DIM,
            (l == 1) ? out : nullptr, (l == 0) ? xmid : nullptr);
    }
}

// Round 11
// 445.696 us; speedup vs baseline: 4.3895x; 1.0620x over previous
//
#include <hip/hip_runtime.h>
#include <hip/hip_bf16.h>

typedef __hip_bfloat16 bf16;
typedef __attribute__((ext_vector_type(8))) short short8;
typedef __attribute__((ext_vector_type(4))) short shortx4;
typedef __attribute__((ext_vector_type(4))) float floatx4;

#define BATCH   2
#define SEQ     1024
#define DIM     1024
#define D_INNER 2048
#define D_STATE 16
#define DT_RANK 64
#define MROWS   (BATCH * SEQ)   // 2048
#define CHUNK   32
#define NCHUNK  (SEQ / CHUNK)   // 32

__device__ __forceinline__ float bf2f(bf16 x) { return __bfloat162float(x); }
__device__ __forceinline__ bf16  f2bf(float x) { return __float2bfloat16(x); }
__device__ __forceinline__ short bfbits(float x) {
    bf16 b = __float2bfloat16(x); short s; __builtin_memcpy(&s, &b, 2); return s;
}

// async global->LDS, 16B per lane (wave-uniform base + lane*16; m104/m108).
__device__ __forceinline__ void ld_lds16(const void* g, void* l) {
    __builtin_amdgcn_global_load_lds(
        (const __attribute__((address_space(1))) void*)g,
        (__attribute__((address_space(3))) void*)l, 16, 0, 0);
}

// ---------------------------------------------------------------------------
// fp32 -> bf16 casts (4 elem/thread); cast2_k fuses two tensors in one grid.
// ---------------------------------------------------------------------------
__device__ __forceinline__ void cast4(const float* in, short* o, int i) {
    floatx4 v = ((const floatx4*)in)[i];
    shortx4 r;
    r.x = bfbits(v.x); r.y = bfbits(v.y); r.z = bfbits(v.z); r.w = bfbits(v.w);
    ((shortx4*)o)[i] = r;
}
__global__ __launch_bounds__(256) void cast_k(
    const float* __restrict__ in, short* __restrict__ o, int n4)
{
    int i = blockIdx.x * 256 + threadIdx.x;
    if (i < n4) cast4(in, o, i);
}
__global__ __launch_bounds__(256) void cast2_k(
    const float* __restrict__ a, short* __restrict__ oa, int na4,
    const float* __restrict__ b, short* __restrict__ ob, int nb4)
{
    int i = blockIdx.x * 256 + threadIdx.x;
    if (i < na4) cast4(a, oa, i);
    else if (i - na4 < nb4) cast4(b, ob, i - na4);
}

// 8 contiguous elements -> short8 bf16 (fp32 converted on the fly).
__device__ __forceinline__ short8 ld8_any(const void* p, size_t eoff, int is_f32) {
    if (is_f32) {
        const float* f = (const float*)p + eoff;
        floatx4 a = *(const floatx4*)f;
        floatx4 b = *(const floatx4*)(f + 4);
        short8 r;
        r[0] = bfbits(a[0]); r[1] = bfbits(a[1]); r[2] = bfbits(a[2]); r[3] = bfbits(a[3]);
        r[4] = bfbits(b[0]); r[5] = bfbits(b[1]); r[6] = bfbits(b[2]); r[7] = bfbits(b[3]);
        return r;
    } else {
        return *(const short8*)((const bf16*)p + eoff);
    }
}

// ---------------------------------------------------------------------------
// gemm128: C[m,n] = sum_k A[m,k]*B[n,k]; 128x128x32 tile, 4 waves (2x2),
// global_load_lds width=16 staging, split-K via blockIdx.z.
// ---------------------------------------------------------------------------
__global__ __launch_bounds__(256) void gemm128(
    const bf16* __restrict__ A, int lda,
    const bf16* __restrict__ B, int ldb,
    float* __restrict__ Cf, bf16* __restrict__ Cb, int ldc,
    int kchunk, size_t psize)
{
    __shared__ short As[128 * 32];
    __shared__ short Bs[128 * 32];
    const int tid  = threadIdx.x;
    const int wave = tid >> 6;
    const int lane = tid & 63;
    const int m0 = blockIdx.y * 128;
    const int n0 = blockIdx.x * 128;
    const int wm = (wave & 1) * 64;
    const int wn = (wave >> 1) * 64;
    const int r16  = lane & 15;
    const int quad = lane >> 4;
    const int r0 = tid >> 2;
    const int c0 = (tid & 3) << 3;
    const int kbeg = blockIdx.z * kchunk;

    floatx4 acc[4][4] = {};

    for (int k0 = kbeg; k0 < kbeg + kchunk; k0 += 32) {
        __syncthreads();
        ld_lds16(A + (size_t)(m0 + r0) * lda + k0 + c0,      As + tid * 8);
        ld_lds16(A + (size_t)(m0 + r0 + 64) * lda + k0 + c0, As + (tid + 256) * 8);
        ld_lds16(B + (size_t)(n0 + r0) * ldb + k0 + c0,      Bs + tid * 8);
        ld_lds16(B + (size_t)(n0 + r0 + 64) * ldb + k0 + c0, Bs + (tid + 256) * 8);
        __syncthreads();
        short8 af[4], bg[4];
#pragma unroll
        for (int i = 0; i < 4; i++) {
            af[i] = *(const short8*)(As + (wm + i * 16 + r16) * 32 + quad * 8);
            bg[i] = *(const short8*)(Bs + (wn + i * 16 + r16) * 32 + quad * 8);
        }
#pragma unroll
        for (int i = 0; i < 4; i++)
#pragma unroll
            for (int j = 0; j < 4; j++)
                acc[i][j] = __builtin_amdgcn_mfma_f32_16x16x32_bf16(af[i], bg[j], acc[i][j], 0, 0, 0);
    }

    float* Cfp = Cf ? Cf + (size_t)blockIdx.z * psize : nullptr;
#pragma unroll
    for (int i = 0; i < 4; i++)
#pragma unroll
        for (int j = 0; j < 4; j++) {
            int gm = m0 + wm + i * 16 + quad * 4;
            int gn = n0 + wn + j * 16 + r16;
#pragma unroll
            for (int r = 0; r < 4; r++) {
                size_t o = (size_t)(gm + r) * ldc + gn;
                float v = acc[i][j][r];
                if (Cfp) Cfp[o] = v;
                if (Cb) Cb[o] = f2bf(v);
            }
        }
}

// ---------------------------------------------------------------------------
// gemm_bt (64x64x32): for N=96 (x_proj, split-K) and K=64 (dt_proj).
// ---------------------------------------------------------------------------
__global__ __launch_bounds__(256) void gemm_bt(
    const void* __restrict__ A, int a_f32, int lda,
    const void* __restrict__ B, int b_f32, int ldb,
    float* __restrict__ Cf, bf16* __restrict__ Cb, int ldc,
    int N, int K, size_t psize,
    const float* __restrict__ bias, int act)
{
    __shared__ short As[64][40];
    __shared__ short Bs[64][40];
    const int m0   = blockIdx.y * 64;
    const int n0   = blockIdx.x * 64;
    const int tid  = threadIdx.x;
    const int wave = tid >> 6;
    const int lane = tid & 63;
    const int srow = tid >> 2;
    const int scol = (tid & 3) << 3;
    const int r16  = lane & 15;
    const int quad = lane >> 4;
    const int kbeg = blockIdx.z * K;

    floatx4 acc[4] = {};

    for (int k0 = kbeg; k0 < kbeg + K; k0 += 32) {
        short8 av = ld8_any(A, (size_t)(m0 + srow) * lda + k0 + scol, a_f32);
        short8 bv = {};
        int gn = n0 + srow;
        if (gn < N) bv = ld8_any(B, (size_t)gn * ldb + k0 + scol, b_f32);
        *(short8*)(&As[srow][scol]) = av;
        *(short8*)(&Bs[srow][scol]) = bv;
        __syncthreads();
        short8 af = *(const short8*)(&As[wave * 16 + r16][quad * 8]);
#pragma unroll
        for (int nt = 0; nt < 4; nt++) {
            short8 bq = *(const short8*)(&Bs[nt * 16 + r16][quad * 8]);
            acc[nt] = __builtin_amdgcn_mfma_f32_16x16x32_bf16(af, bq, acc[nt], 0, 0, 0);
        }
        __syncthreads();
    }

    float* Cfp = Cf ? Cf + (size_t)blockIdx.z * psize : nullptr;
#pragma unroll
    for (int nt = 0; nt < 4; nt++) {
        int gn = n0 + nt * 16 + r16;
        if (gn >= N) continue;
        float bsv = bias ? bias[gn] : 0.f;
#pragma unroll
        for (int r = 0; r < 4; r++) {
            int gm = m0 + wave * 16 + quad * 4 + r;
            float v = acc[nt][r] + bsv;
            if (act == 1) v = (v > 20.f) ? v : log1pf(__expf(v));  // softplus
            size_t o = (size_t)gm * ldc + gn;
            if (Cfp) Cfp[o] = v;
            if (Cb) Cb[o] = f2bf(v);
        }
    }
}

// sum 8 split-K partials -> fp32
__global__ __launch_bounds__(256) void reduce8_k(
    const float* __restrict__ part, float* __restrict__ o, int n, size_t psize)
{
    int i = blockIdx.x * 256 + threadIdx.x;
    if (i >= n) return;
    float v = 0.f;
#pragma unroll
    for (int j = 0; j < 8; j++) v += part[i + (size_t)j * psize];
    o[i] = v;
}

// sum 2 split-K partials -> fp32 and/or bf16
__global__ __launch_bounds__(256) void reduce2_k(
    const float* __restrict__ part, size_t psize, int n,
    float* __restrict__ of, bf16* __restrict__ ob)
{
    int i = blockIdx.x * 256 + threadIdx.x;
    if (i >= n) return;
    float v = part[i] + part[i + psize];
    if (of) of[i] = v;
    if (ob) ob[i] = f2bf(v);
}

// ---------------------------------------------------------------------------
// Depthwise causal conv (4 taps) + bias + SiLU over xi = xz[:, :, 0:2048].
// ---------------------------------------------------------------------------
__global__ __launch_bounds__(256) void conv_silu_k(
    const bf16* __restrict__ xz, const float* __restrict__ cw,
    const float* __restrict__ cb, bf16* __restrict__ xcb)
{
    int idx = blockIdx.x * 256 + threadIdx.x;      // bt*2048 + d
    int d   = idx & (D_INNER - 1);
    int bt  = idx >> 11;
    int t   = bt & (SEQ - 1);
    float s = cb[d];
#pragma unroll
    for (int j = 0; j < 4; j++) {
        int tt = t - 3 + j;
        if (tt >= 0) s += cw[d * 4 + j] * bf2f(xz[(size_t)(bt - 3 + j) * 4096 + d]);
    }
    float sig = 1.f / (1.f + __expf(-s));
    xcb[idx] = f2bf(s * sig);
}

// ---------------------------------------------------------------------------
// Selective scan (chunk-parallel, channel-per-thread, bulk LDS staging).
// R11: 3-phase. scan1 -> per-chunk local states S + sum(dt); scanpre ->
// in-place prefix turning cS into per-chunk h_init (removes scan2's serial
// rebuild: ~138 MB redundant latency-exposed traffic per layer); scan2 ->
// re-scan chunk from h_init, fused y-dot + D*xc + silu(z) gating.
// ---------------------------------------------------------------------------
__global__ __launch_bounds__(256) void scan1_k(
    const float* __restrict__ dtf, const bf16* __restrict__ xcb,
    const float* __restrict__ xdbl, const float* __restrict__ Alog,
    float* __restrict__ chunk_sdt, float* __restrict__ chunk_S)
{
    __shared__ float dt_s[CHUNK][256];
    __shared__ short xc_s[CHUNK][256];
    __shared__ float B_s[CHUNK][16];
    const int tid = threadIdx.x;
    const int d0  = blockIdx.x * 256;
    const int d   = d0 + tid;
    const int b   = blockIdx.y;
    const int c   = blockIdx.z;
    const size_t rbase = (size_t)b * SEQ + c * CHUNK;

#pragma unroll 4
    for (int t = 0; t < CHUNK; t++) {
        dt_s[t][tid] = dtf[(rbase + t) * D_INNER + d0 + tid];
        ((short*)xc_s)[t * 256 + tid] = *(const short*)&xcb[(rbase + t) * D_INNER + d0 + tid];
    }
    for (int e = tid; e < CHUNK * 16; e += 256) {
        int t = e >> 4, n = e & 15;
        B_s[t][n] = xdbl[(rbase + t) * 96 + 64 + n];
    }
    float A[16];
#pragma unroll
    for (int n = 0; n < 16; n++) A[n] = -__expf(Alog[(size_t)d * 16 + n]);
    float h[16] = {};
    float sdt = 0.f;
    __syncthreads();

    for (int t = 0; t < CHUNK; t++) {
        float dtv = dt_s[t][tid];
        bf16 xcr; short xs = xc_s[t][tid]; __builtin_memcpy(&xcr, &xs, 2);
        float u = dtv * bf2f(xcr);
        sdt += dtv;
        floatx4 B0 = *(const floatx4*)&B_s[t][0];
        floatx4 B1 = *(const floatx4*)&B_s[t][4];
        floatx4 B2 = *(const floatx4*)&B_s[t][8];
        floatx4 B3 = *(const floatx4*)&B_s[t][12];
#pragma unroll
        for (int n = 0; n < 4; n++) {
            h[n]      = __expf(dtv * A[n])      * h[n]      + u * B0[n];
            h[n + 4]  = __expf(dtv * A[n + 4])  * h[n + 4]  + u * B1[n];
            h[n + 8]  = __expf(dtv * A[n + 8])  * h[n + 8]  + u * B2[n];
            h[n + 12] = __expf(dtv * A[n + 12]) * h[n + 12] + u * B3[n];
        }
    }
    chunk_sdt[(b * NCHUNK + c) * D_INNER + d] = sdt;
#pragma unroll
    for (int n = 0; n < 16; n++)
        chunk_S[((size_t)(b * NCHUNK + c) * 16 + n) * D_INNER + d] = h[n];
}

// grid (D_INNER/256, BATCH, D_STATE); in-place prefix over chunks.
// Combine order identical to the old scan2 rebuild -> bit-identical result.
__global__ __launch_bounds__(256) void scanpre_k(
    const float* __restrict__ Alog, const float* __restrict__ chunk_sdt,
    float* __restrict__ chunk_S)
{
    const int d = blockIdx.x * 256 + threadIdx.x;
    const int b = blockIdx.y;
    const int n = blockIdx.z;
    const float Av = -__expf(Alog[(size_t)d * 16 + n]);
    float h = 0.f;
    for (int j = 0; j < NCHUNK; j++) {
        size_t si = ((size_t)(b * NCHUNK + j) * 16 + n) * D_INNER + d;
        float S   = chunk_S[si];
        float sdt = chunk_sdt[(b * NCHUNK + j) * D_INNER + d];
        chunk_S[si] = h;                      // h_init for chunk j
        h = __expf(sdt * Av) * h + S;
    }
}

__global__ __launch_bounds__(256) void scan2_k(
    const float* __restrict__ dtf, const bf16* __restrict__ xcb,
    const float* __restrict__ xdbl, const bf16* __restrict__ xz,
    const float* __restrict__ Alog, const float* __restrict__ Dp,
    const float* __restrict__ chunk_S, bf16* __restrict__ yb)
{
    __shared__ float dt_s[CHUNK][256];
    __shared__ short xc_s[CHUNK][256];
    __shared__ float B_s[CHUNK][16];
    __shared__ float C_s[CHUNK][16];
    const int tid = threadIdx.x;
    const int d0  = blockIdx.x * 256;
    const int d   = d0 + tid;
    const int b   = blockIdx.y;
    const int c   = blockIdx.z;
    const size_t rbase = (size_t)b * SEQ + c * CHUNK;

#pragma unroll 4
    for (int t = 0; t < CHUNK; t++) {
        dt_s[t][tid] = dtf[(rbase + t) * D_INNER + d0 + tid];
        ((short*)xc_s)[t * 256 + tid] = *(const short*)&xcb[(rbase + t) * D_INNER + d0 + tid];
    }
    for (int e = tid; e < CHUNK * 16; e += 256) {
        int t = e >> 4, n = e & 15;
        B_s[t][n] = xdbl[(rbase + t) * 96 + 64 + n];
        C_s[t][n] = xdbl[(rbase + t) * 96 + 80 + n];
    }
    float A[16];
#pragma unroll
    for (int n = 0; n < 16; n++) A[n] = -__expf(Alog[(size_t)d * 16 + n]);

    float h[16];
#pragma unroll
    for (int n = 0; n < 16; n++)
        h[n] = chunk_S[((size_t)(b * NCHUNK + c) * 16 + n) * D_INNER + d];

    const float Dv = Dp[d];
    __syncthreads();

    for (int t = 0; t < CHUNK; t++) {
        size_t row = rbase + t;
        float dtv = dt_s[t][tid];
        bf16 xcr; short xs = xc_s[t][tid]; __builtin_memcpy(&xcr, &xs, 2);
        float xcv = bf2f(xcr);
        float u = dtv * xcv;
        floatx4 B0 = *(const floatx4*)&B_s[t][0];
        floatx4 B1 = *(const floatx4*)&B_s[t][4];
        floatx4 B2 = *(const floatx4*)&B_s[t][8];
        floatx4 B3 = *(const floatx4*)&B_s[t][12];
        floatx4 C0 = *(const floatx4*)&C_s[t][0];
        floatx4 C1 = *(const floatx4*)&C_s[t][4];
        floatx4 C2 = *(const floatx4*)&C_s[t][8];
        floatx4 C3 = *(const floatx4*)&C_s[t][12];
        float y = 0.f;
#pragma unroll
        for (int n = 0; n < 4; n++) {
            h[n]      = __expf(dtv * A[n])      * h[n]      + u * B0[n];
            h[n + 4]  = __expf(dtv * A[n + 4])  * h[n + 4]  + u * B1[n];
            h[n + 8]  = __expf(dtv * A[n + 8])  * h[n + 8]  + u * B2[n];
            h[n + 12] = __expf(dtv * A[n + 12]) * h[n + 12] + u * B3[n];
            y += h[n] * C0[n] + h[n + 4] * C1[n] + h[n + 8] * C2[n] + h[n + 12] * C3[n];
        }
        float zv = bf2f(xz[row * 4096 + 2048 + d]);
        y = (y + Dv * xcv) * (zv / (1.f + __expf(-zv)));
        yb[row * D_INNER + d] = f2bf(y);
    }
}

extern "C" void kernel_launch(void* const* d_in, const int* in_sizes, int n_in,
                              void* d_out, int out_size, void* d_ws, size_t ws_size,
                              hipStream_t stream)
{
    // ALL inputs fp32; OUTPUT IS FP32.
    const float* x    = (const float*)d_in[0];
    const float* inw  = (const float*)d_in[1];
    const float* cw   = (const float*)d_in[2];
    const float* cb   = (const float*)d_in[3];
    const float* xpw  = (const float*)d_in[4];
    const float* dtw  = (const float*)d_in[5];
    const float* dtb  = (const float*)d_in[6];
    const float* Alog = (const float*)d_in[7];
    const float* Dp   = (const float*)d_in[8];
    const float* ow   = (const float*)d_in[9];
    float* out = (float*)d_out;

    // workspace layout (~87 MB; fills show ws >= 268 MB)
    char* p = (char*)d_ws;
    bf16*  xzb   = (bf16*)p;  p += (size_t)MROWS * 4096 * 2;        // 16.8 MB
    bf16*  xcb   = (bf16*)p;  p += (size_t)MROWS * D_INNER * 2;     //  8.4 MB
    float* xdblf = (float*)p; p += (size_t)MROWS * 96 * 4;          //  0.8 MB
    float* dtf   = (float*)p; p += (size_t)MROWS * D_INNER * 4;     // 16.8 MB
    bf16*  ybf   = (bf16*)p;  p += (size_t)MROWS * D_INNER * 2;     //  8.4 MB
    bf16*  xmid  = (bf16*)p;  p += (size_t)MROWS * DIM * 2;         //  4.2 MB
    float* csdt  = (float*)p; p += (size_t)BATCH * NCHUNK * D_INNER * 4;      // 0.5 MB
    float* cS    = (float*)p; p += (size_t)BATCH * NCHUNK * 16 * D_INNER * 4; // 8.4 MB
    bf16*  xb    = (bf16*)p;  p += (size_t)MROWS * DIM * 2;         //  4.2 MB
    bf16*  inwb  = (bf16*)p;  p += (size_t)2 * D_INNER * DIM * 2;   //  8.4 MB (one layer)
    bf16*  owb   = (bf16*)p;  p += (size_t)DIM * D_INNER * 2;       //  4.2 MB (one layer)
    float* xprt  = (float*)p; p += (size_t)8 * MROWS * 96 * 4;      //  6.3 MB

    const size_t xp_psize = (size_t)MROWS * 96;
    const size_t op_psize = (size_t)MROWS * DIM;
    float* outp = dtf;   // dtf dead after scans; holds 2 out_proj partials

    // input cast (once)
    cast_k<<<(MROWS * DIM / 4 + 255) / 256, 256, 0, stream>>>(x, (short*)xb, MROWS * DIM / 4);

    for (int l = 0; l < 2; l++) {
        const float* xpw_l = xpw + (size_t)l * 96 * D_INNER;
        const float* dtw_l = dtw + (size_t)l * D_INNER * DT_RANK;
        const float* Al    = Alog + (size_t)l * D_INNER * D_STATE;

        // 0. cast this layer's big weights to bf16 (fused single dispatch)
        {
            int na4 = 2 * D_INNER * DIM / 4, nb4 = DIM * D_INNER / 4;
            cast2_k<<<(na4 + nb4 + 255) / 256, 256, 0, stream>>>(
                inw + (size_t)l * 2 * D_INNER * DIM, (short*)inwb, na4,
                ow + (size_t)l * DIM * D_INNER, (short*)owb, nb4);
        }

        // 1. xz = xin @ in_proj_w^T   (M=2048, N=4096, K=1024), bf16 out
        gemm128<<<dim3(32, 16, 1), 256, 0, stream>>>(
            (l == 0) ? xb : xmid, DIM, inwb, DIM,
            nullptr, xzb, 4096, DIM, 0);

        // 2. causal depthwise conv + bias + SiLU
        conv_silu_k<<<(MROWS * D_INNER) / 256, 256, 0, stream>>>(
            xzb, cw + (size_t)l * D_INNER * 4, cb + (size_t)l * D_INNER, xcb);

        // 3. x_dbl = xc @ x_proj_w^T   (N=96, K=2048), split-K=8 + reduce
        gemm_bt<<<dim3(2, 32, 8), 256, 0, stream>>>(
            xcb, 0, D_INNER, xpw_l, 1, D_INNER,
            xprt, nullptr, 96, 96, 256, xp_psize, nullptr, 0);
        reduce8_k<<<(MROWS * 96 + 255) / 256, 256, 0, stream>>>(
            xprt, xdblf, MROWS * 96, xp_psize);

        // 4. dt = softplus(dt_raw @ dt_proj_w^T + dt_b)  (N=2048, K=64), fp32
        gemm_bt<<<dim3(32, 32), 256, 0, stream>>>(
            xdblf, 1, 96, dtw_l, 1, DT_RANK,
            dtf, nullptr, D_INNER, D_INNER, DT_RANK, 0,
            dtb + (size_t)l * D_INNER, 1);

        // 5. chunk-parallel selective scan (3 phases) + gating epilogue
        scan1_k<<<dim3(D_INNER / 256, BATCH, NCHUNK), 256, 0, stream>>>(
            dtf, xcb, xdblf, Al, csdt, cS);
        scanpre_k<<<dim3(D_INNER / 256, BATCH, D_STATE), 256, 0, stream>>>(
            Al, csdt, cS);
        scan2_k<<<dim3(D_INNER / 256, BATCH, NCHUNK), 256, 0, stream>>>(
            dtf, xcb, xdblf, xzb, Al, Dp + (size_t)l * D_INNER, cS, ybf);

        // 6. out = y @ out_proj_w^T   (N=1024, K=2048), split-K=2 + reduce
        gemm128<<<dim3(8, 16, 2), 256, 0, stream>>>(
            ybf, D_INNER, owb, D_INNER,
            outp, nullptr, DIM, D_INNER / 2, op_psize);
        reduce2_k<<<(MROWS * DIM + 255) / 256, 256, 0, stream>>>(
            outp, op_psize, MROWS * DIM,
            (l == 1) ? out : nullptr, (l == 0) ? xmid : nullptr);
    }
}